// Round 1
// baseline (323.061 us; speedup 1.0000x reference)
//
#include <hip/hip_runtime.h>
#include <hip/hip_bf16.h>

// Problem constants (fixed by the reference setup)
constexpr int SLI  = 8;
constexpr int FEAT = 64;
constexpr int NODE = 20000;
constexpr int NTOT = SLI * NODE;   // 160000
constexpr int OUTF = 64;
constexpr int CAP  = 48;           // ELL capacity; max in-deg for Poisson(16)@160k ~ 36-40
constexpr int NB   = 313;          // buckets of 512 global node ids (key = id >> 9)
constexpr int BCAP = 8960;         // bucket capacity; mean 8192, +8.5 sigma
constexpr int EPB  = 4096;         // edges per partition block (16/thread)
constexpr int NDST = NTOT / 256;   // 625 fin blocks (half-bucket each)

typedef __attribute__((ext_vector_type(8))) short bf16x8;
typedef __attribute__((ext_vector_type(4))) float f32x4;

static __device__ inline unsigned short f2bf(float x) {
    unsigned u = __float_as_uint(x);
    unsigned r = (u + 0x7fffu + ((u >> 16) & 1u)) >> 16;   // round-to-nearest-even
    return (unsigned short)r;
}

// ---------------------------------------------------------------------------
// 1) partition: one read of (src,dst); LDS counting-sort by dst-bucket only
//    (packed (dst_local<<18)|src). deg_out via direct global atomics
//    (2.56M adds over 160K counters ~ 16/addr -> low contention); this kills
//    the entire src-bucket path (2 LDS atomics/edge + scan + 5.6MB traffic).
__global__ __launch_bounds__(256) void k_part(const int* __restrict__ src,
                                              const int* __restrict__ dst,
                                              int* __restrict__ cursor_d,
                                              unsigned* __restrict__ bucket_d,
                                              int* __restrict__ deg_out, int E) {
    __shared__ unsigned       svalD[EPB];   // 16KB
    __shared__ unsigned short sbktD[EPB];   // 8KB
    __shared__ int histD[NB], loffD[NB], lcurD[NB], baseD[NB];
    __shared__ int goffD[64];               // ~29KB total -> 5 blocks/CU
    int t  = threadIdx.x;
    int e0 = blockIdx.x * EPB;
    for (int i = t; i < NB; i += 256) histD[i] = 0;
    __syncthreads();
    int myS[16], myD[16];
#pragma unroll
    for (int i = 0; i < 16; ++i) {
        int idx = e0 + i * 256 + t;                      // coalesced
        if (idx < E) {
            myS[i] = src[idx];
            myD[i] = dst[idx];
            atomicAdd(&histD[myD[i] >> 9], 1);
            atomicAdd(&deg_out[myS[i]], 1);              // global, spread wide
        } else { myS[i] = -1; myD[i] = -1; }
    }
    __syncthreads();
    // exclusive scan of histD: wave 0, 64 groups of 5
    int wv = t >> 6, ln = t & 63;
    if (wv == 0) {
        int b0 = ln * 5, s = 0;
#pragma unroll
        for (int j = 0; j < 5; ++j) { int bb = b0 + j; if (bb < NB) s += histD[bb]; }
        int x = s;
        for (int off = 1; off < 64; off <<= 1) {
            int y = __shfl_up(x, off, 64);
            if (ln >= off) x += y;
        }
        goffD[ln] = x - s;
    }
    __syncthreads();
    for (int bb = t; bb < NB; bb += 256) {
        int g5 = bb / 5;
        int sD = goffD[g5];
        for (int k = g5 * 5; k < bb; ++k) sD += histD[k];
        loffD[bb] = sD; lcurD[bb] = sD;
        baseD[bb] = atomicAdd(&cursor_d[bb], histD[bb]);   // reserve global run
    }
    __syncthreads();
#pragma unroll
    for (int i = 0; i < 16; ++i) {
        if (myD[i] >= 0) {
            int bD = myD[i] >> 9;
            int p  = atomicAdd(&lcurD[bD], 1);
            svalD[p] = ((unsigned)(myD[i] & 511) << 18) | (unsigned)myS[i];
            sbktD[p] = (unsigned short)bD;
        }
    }
    __syncthreads();
    int nval = E - e0; if (nval > EPB) nval = EPB;
    for (int p = t; p < nval; p += 256) {                // coalesced runs
        int bD = sbktD[p];
        int wi = baseD[bD] + (p - loffD[bD]);
        if (wi < BCAP) bucket_d[(size_t)bD * BCAP + wi] = svalD[p];
    }
}

// 2) finalize: build ELL from dst-buckets (src path gone -> 625 blocks only)
__global__ __launch_bounds__(256) void k_fin(const int* __restrict__ cursor_d,
                                             const unsigned* __restrict__ bucket_d,
                                             int* __restrict__ col_ell,
                                             int* __restrict__ deg_in) {
    __shared__ char lds[256 * CAP * 4 + 1024];           // ~50 KB
    int* ell = (int*)lds;                                // 256*CAP ints
    int* cnt = (int*)(lds + 256 * CAP * 4);              // 256 ints
    int t = threadIdx.x;
    int blk = blockIdx.x, b = blk >> 1, half = blk & 1;
    cnt[t] = 0;
    __syncthreads();
    int len = cursor_d[b]; if (len > BCAP) len = BCAP;
    const unsigned* p = bucket_d + (size_t)b * BCAP;
    for (int i = t; i < len; i += 256) {                 // coalesced read
        unsigned e = p[i];
        int dl = e >> 18;
        if ((dl >> 8) == half) {
            int r = dl & 255;
            int pos = atomicAdd(&cnt[r], 1);             // LDS atomic
            if (pos < CAP) ell[r * CAP + pos] = (int)(e & 0x3FFFFu);
        }
    }
    __syncthreads();
    int node0 = blk << 8;
    deg_in[node0 + t] = cnt[t];
    size_t gbase = (size_t)node0 * CAP;                  // 256*CAP = 12288 dwords
    const int4* lsrc = (const int4*)ell;
    int4* gdst = (int4*)(col_ell + gbase);
#pragma unroll
    for (int i = 0; i < 12; ++i)
        gdst[i * 256 + t] = lsrc[i * 256 + t];           // coalesced dwordx4
}

// 3) transpose inputs [SLI][FEAT][NODE] (f32) -> xs [NTOT][FEAT] (bf16), scaled by
//    rsqrt(deg_out). float4 global loads, packed 2xbf16 uint stores.
__global__ __launch_bounds__(256) void k_transpose(const float* __restrict__ in,
                                                   const int* __restrict__ deg_out,
                                                   unsigned short* __restrict__ xs) {
    __shared__ float tile[64][65];
    int sli = blockIdx.y;
    int n0  = blockIdx.x * 64;
    int t   = threadIdx.x;
    int fx  = t & 15;        // node quad
    int fr  = t >> 4;        // feat
    const float* ip = in + (size_t)sli * FEAT * NODE;
    int nq = n0 + fx * 4;
#pragma unroll
    for (int i = 0; i < 4; ++i) {
        int f = fr + i * 16;
        float4 v = {0.f, 0.f, 0.f, 0.f};
        if (nq < NODE) v = *(const float4*)(ip + (size_t)f * NODE + nq);  // coalesced 16B
        tile[f][fx * 4 + 0] = v.x;
        tile[f][fx * 4 + 1] = v.y;
        tile[f][fx * 4 + 2] = v.z;
        tile[f][fx * 4 + 3] = v.w;
    }
    __syncthreads();
    int h  = t & 31;         // feat pair: feats 2h, 2h+1
    int nr = t >> 5;
#pragma unroll
    for (int i = 0; i < 8; ++i) {
        int nl   = nr + i * 8;
        int node = n0 + nl;
        if (node < NODE) {
            int n = sli * NODE + node;
            int d = deg_out[n];
            float sc = rsqrtf(d > 0 ? (float)d : 1.f);
            unsigned lo = f2bf(tile[2 * h][nl] * sc);
            unsigned hi = f2bf(tile[2 * h + 1][nl] * sc);
            *(unsigned*)(xs + (size_t)n * 64 + 2 * h) = lo | (hi << 16);  // coalesced
        }
    }
}

// 4) fused ELL gather (8-lane x 16B, FOUR rows in flight + unroll-2 group loop
//    -> up to 8 outstanding 16B gathers/wave, zero-pad row -> no divergence)
//    + MFMA dense + bias + LeakyReLU + transposed store
__global__ __launch_bounds__(256) void k_agg_gemm(const int* __restrict__ deg_in,
                                                  const int* __restrict__ col_ell,
                                                  const unsigned short* __restrict__ xs,
                                                  const float* __restrict__ W,
                                                  const float* __restrict__ b,
                                                  float* __restrict__ out) {
    // LDS: av [64][72] bf16 @0 (9216) | wt [64][72] bf16 @9216 (9216) = 18432 B
    // otile [64][65] f32 (16640) aliases av+wt after the post-MFMA barrier.
    __shared__ char lds[18432];
    unsigned short* av = (unsigned short*)lds;
    unsigned short* wt = (unsigned short*)(lds + 9216);
    float (*otile)[65] = (float(*)[65])lds;

    int t    = threadIdx.x;
    int lane = t & 63;
    int w    = t >> 6;          // wave 0..3
    int g8   = lane >> 3;       // edge group 0..7
    int f8   = lane & 7;        // feat octet: feats 8*f8 .. 8*f8+7
    int sli  = blockIdx.y;
    int n0   = blockIdx.x * 64;

    // ---- stage Wt[out][feat] = bf16(W[feat][out]) ----
#pragma unroll
    for (int i = 0; i < 16; ++i) {
        int idx = i * 256 + t;          // idx = f*64 + o
        int f = idx >> 6, o = idx & 63;
        wt[o * 72 + f] = f2bf(W[idx]);
    }

    // ---- gather: wave w owns rows [m0, m0+16), FOUR rows in flight ----
    int m0 = w * 16;
    for (int ii = 0; ii < 16; ii += 4) {
        int dg[4], col[4];
        int gmax = 0;
#pragma unroll
        for (int r = 0; r < 4; ++r) {
            int node = n0 + m0 + ii + r;
            int n    = sli * NODE + node;
            int d    = (node < NODE) ? deg_in[n] : 0;
            dg[r] = d;
            int dc = d < CAP ? d : CAP;
            if (dc > gmax) gmax = dc;
            // pad lanes point at the zeroed xs row NTOT -> no guards inside
            col[r] = (lane < dc) ? col_ell[(size_t)n * CAP + lane] : NTOT;
        }
        float acc[4][8];
#pragma unroll
        for (int r = 0; r < 4; ++r)
#pragma unroll
            for (int k = 0; k < 8; ++k) acc[r][k] = 0.f;
        int groups = (gmax + 7) >> 3;
#pragma unroll 2
        for (int j = 0; j < groups; ++j) {
            int idx = 8 * j + g8;
            uint4 v[4];
#pragma unroll
            for (int r = 0; r < 4; ++r) {
                int s = __shfl(col[r], idx, 64);
                v[r] = *(const uint4*)(xs + (size_t)s * 64 + f8 * 8);   // 16B
            }
#pragma unroll
            for (int r = 0; r < 4; ++r) {
                acc[r][0] += __uint_as_float(v[r].x << 16);
                acc[r][1] += __uint_as_float(v[r].x & 0xffff0000u);
                acc[r][2] += __uint_as_float(v[r].y << 16);
                acc[r][3] += __uint_as_float(v[r].y & 0xffff0000u);
                acc[r][4] += __uint_as_float(v[r].z << 16);
                acc[r][5] += __uint_as_float(v[r].z & 0xffff0000u);
                acc[r][6] += __uint_as_float(v[r].w << 16);
                acc[r][7] += __uint_as_float(v[r].w & 0xffff0000u);
            }
        }
        // reduce over the 8 edge groups (lanes with same f8, stride 8)
#pragma unroll
        for (int r = 0; r < 4; ++r)
#pragma unroll
            for (int k = 0; k < 8; ++k) {
                acc[r][k] += __shfl_xor(acc[r][k], 8, 64);
                acc[r][k] += __shfl_xor(acc[r][k], 16, 64);
                acc[r][k] += __shfl_xor(acc[r][k], 32, 64);
            }
        if (g8 == 0) {    // lanes 0..7 hold feats 8*f8..8*f8+7
#pragma unroll
            for (int r = 0; r < 4; ++r) {
                float sc = rsqrtf(dg[r] > 0 ? (float)dg[r] : 1.f);
                uint4 hv;
                hv.x = (unsigned)f2bf(acc[r][0] * sc) | ((unsigned)f2bf(acc[r][1] * sc) << 16);
                hv.y = (unsigned)f2bf(acc[r][2] * sc) | ((unsigned)f2bf(acc[r][3] * sc) << 16);
                hv.z = (unsigned)f2bf(acc[r][4] * sc) | ((unsigned)f2bf(acc[r][5] * sc) << 16);
                hv.w = (unsigned)f2bf(acc[r][6] * sc) | ((unsigned)f2bf(acc[r][7] * sc) << 16);
                ((uint4*)(av + (m0 + ii + r) * 72))[f8] = hv;
            }
        }
    }

    __syncthreads();   // wt + av complete

    // ---- MFMA: O[16 nodes][64 outs] per wave, K=64 ----
    int q = lane >> 4, r16 = lane & 15;
    bf16x8 afr[2], bfr[4][2];
#pragma unroll
    for (int ks = 0; ks < 2; ++ks)
        afr[ks] = *(const bf16x8*)(av + (m0 + r16) * 72 + ks * 32 + q * 8);
#pragma unroll
    for (int nt = 0; nt < 4; ++nt)
#pragma unroll
        for (int ks = 0; ks < 2; ++ks)
            bfr[nt][ks] = *(const bf16x8*)(wt + (nt * 16 + r16) * 72 + ks * 32 + q * 8);

    f32x4 acc4[4];
#pragma unroll
    for (int nt = 0; nt < 4; ++nt) acc4[nt] = (f32x4){0.f, 0.f, 0.f, 0.f};
#pragma unroll
    for (int nt = 0; nt < 4; ++nt)
#pragma unroll
        for (int ks = 0; ks < 2; ++ks)
            acc4[nt] = __builtin_amdgcn_mfma_f32_16x16x32_bf16(afr[ks], bfr[nt][ks], acc4[nt], 0, 0, 0);
    __syncthreads();   // av/wt reads done; safe to alias otile

    // ---- epilogue: bias + LeakyReLU -> otile[out][node_local] ----
#pragma unroll
    for (int nt = 0; nt < 4; ++nt) {
        int oc = nt * 16 + r16;
        float bias = b[oc];
#pragma unroll
        for (int r = 0; r < 4; ++r) {
            float v = acc4[nt][r] + bias;
            v = v > 0.f ? v : 0.01f * v;               // LeakyReLU
            otile[oc][m0 + q * 4 + r] = v;
        }
    }
    __syncthreads();

    const size_t obase = (size_t)sli * OUTF * NODE;
#pragma unroll
    for (int i = 0; i < 16; ++i) {
        int o    = w + i * 4;
        int node = n0 + lane;
        if (node < NODE)
            out[obase + (size_t)o * NODE + node] = otile[o][lane];   // coalesced
    }
}

// ---------------------------------------------------------------------------
extern "C" void kernel_launch(void* const* d_in, const int* in_sizes, int n_in,
                              void* d_out, int out_size, void* d_ws, size_t ws_size,
                              hipStream_t stream) {
    const float* inputs = (const float*)d_in[0];
    const float* W      = (const float*)d_in[1];
    const float* b      = (const float*)d_in[2];
    const int*   src    = (const int*)d_in[3];
    const int*   dst    = (const int*)d_in[4];
    float*       out    = (float*)d_out;
    const int E = in_sizes[3];

    // Workspace (~52.5 MB, unchanged footprint): deg_out | deg_in | col_ell | R
    // R holds bucket_d+cursor_d during build; xs (+zero pad row NTOT) overlays R
    // afterwards (bucket/cursor dead once k_fin completes). bucket_s is GONE.
    char* ws = (char*)d_ws;
    int* deg_out = (int*)ws;
    int* deg_in  = (int*)(ws + (size_t)NTOT * 4);
    int* col_ell = (int*)(ws + (size_t)2 * NTOT * 4);
    char* R      = (char*)col_ell + (size_t)NTOT * CAP * 4;
    unsigned* bucket_d = (unsigned*)R;                        // 11.22 MB
    int*      cursor_d = (int*)(R + (size_t)NB * BCAP * 4);   // 1.25 KB
    unsigned short* xs = (unsigned short*)R;   // (NTOT+1)*64 bf16 overlay (20.48 MB)

    hipMemsetAsync(cursor_d, 0, (size_t)NB * 4, stream);
    hipMemsetAsync(deg_out, 0, (size_t)NTOT * 4, stream);     // atomic accumulator
    hipMemsetAsync(xs + (size_t)NTOT * 64, 0, 64 * sizeof(unsigned short), stream); // pad row

    int PB = (E + EPB - 1) / EPB;
    k_part<<<PB, 256, 0, stream>>>(src, dst, cursor_d, bucket_d, deg_out, E);

    k_fin<<<NDST, 256, 0, stream>>>(cursor_d, bucket_d, col_ell, deg_in);

    dim3 tgrid((NODE + 63) / 64, SLI);
    k_transpose<<<tgrid, 256, 0, stream>>>(inputs, deg_out, xs);

    k_agg_gemm<<<tgrid, 256, 0, stream>>>(deg_in, col_ell, xs, W, b, out);
}

// Round 2
// 270.553 us; speedup vs baseline: 1.1941x; 1.1941x over previous
//
#include <hip/hip_runtime.h>
#include <hip/hip_bf16.h>

// Problem constants (fixed by the reference setup)
constexpr int SLI  = 8;
constexpr int FEAT = 64;
constexpr int NODE = 20000;
constexpr int NTOT = SLI * NODE;   // 160000
constexpr int OUTF = 64;
constexpr int CAP  = 48;           // ELL capacity; max in-deg for Poisson(16)@160k ~ 36-40
constexpr int NB   = 313;          // buckets of 512 global node ids (key = id >> 9)
constexpr int BCAP = 8960;         // bucket capacity; mean 8192, +8.5 sigma
constexpr int EPB  = 2048;         // edges per partition block (8/thread) -> 1250 blocks
constexpr int NDST = NTOT / 256;   // 625 fin_dst blocks

typedef __attribute__((ext_vector_type(8))) short bf16x8;
typedef __attribute__((ext_vector_type(4))) float f32x4;

static __device__ inline unsigned short f2bf(float x) {
    unsigned u = __float_as_uint(x);
    unsigned r = (u + 0x7fffu + ((u >> 16) & 1u)) >> 16;   // round-to-nearest-even
    return (unsigned short)r;
}

// ---------------------------------------------------------------------------
// 1) fused partition: one int4-vectorized read of (src,dst); LDS counting-sort
//    by dst-bucket (packed (dst_local<<18)|src) AND by src-bucket
//    (packed (bS<<9)|src_local). deg_out via bucket counting in k_fin — NO
//    scattered global atomics (round-1 lesson: 2.56M global atomicAdds cost
//    ~84MB of RMW write traffic and ~50us of serialized latency).
//    EPB=2048 -> 1250 blocks (~4.9/CU); LDS ~31KB -> 5 blocks/CU fit.
__global__ __launch_bounds__(256) void k_part(const int* __restrict__ src,
                                              const int* __restrict__ dst,
                                              int* __restrict__ cursor_d,
                                              unsigned* __restrict__ bucket_d,
                                              int* __restrict__ cursor_s,
                                              unsigned short* __restrict__ bucket_s, int E) {
    __shared__ unsigned       svalD[EPB];   // 8KB
    __shared__ unsigned short sbktD[EPB];   // 4KB
    __shared__ unsigned sS[EPB];            // 8KB: (bS<<9)|src_local
    __shared__ int histD[NB], loffD[NB], lcurD[NB], baseD[NB];
    __shared__ int histS[NB], loffS[NB], lcurS[NB], baseS[NB];
    __shared__ int goffD[64], goffS[64];
    int t  = threadIdx.x;
    int e0 = blockIdx.x * EPB;
    for (int i = t; i < NB; i += 256) { histD[i] = 0; histS[i] = 0; }
    __syncthreads();
    int myS[8], myD[8];
#pragma unroll
    for (int i = 0; i < 2; ++i) {
        int j  = (e0 >> 2) + i * 256 + t;   // int4 index, coalesced 16B
        int b4 = j << 2;
        if (b4 + 3 < E) {
            int4 vs = ((const int4*)src)[j];
            int4 vd = ((const int4*)dst)[j];
            myS[4*i+0] = vs.x; myS[4*i+1] = vs.y; myS[4*i+2] = vs.z; myS[4*i+3] = vs.w;
            myD[4*i+0] = vd.x; myD[4*i+1] = vd.y; myD[4*i+2] = vd.z; myD[4*i+3] = vd.w;
        } else {
#pragma unroll
            for (int c = 0; c < 4; ++c) {
                int idx = b4 + c;
                myS[4*i+c] = (idx < E) ? src[idx] : -1;
                myD[4*i+c] = (idx < E) ? dst[idx] : -1;
            }
        }
    }
#pragma unroll
    for (int i = 0; i < 8; ++i) {
        if (myD[i] >= 0) {
            atomicAdd(&histD[myD[i] >> 9], 1);
            atomicAdd(&histS[myS[i] >> 9], 1);
        }
    }
    __syncthreads();
    // exclusive scans of histD/histS: wave 0 scans D, wave 1 scans S (64 groups of 5)
    int wv = t >> 6, ln = t & 63;
    if (wv == 0) {
        int b0 = ln * 5, s = 0;
#pragma unroll
        for (int j = 0; j < 5; ++j) { int bb = b0 + j; if (bb < NB) s += histD[bb]; }
        int x = s;
        for (int off = 1; off < 64; off <<= 1) {
            int y = __shfl_up(x, off, 64);
            if (ln >= off) x += y;
        }
        goffD[ln] = x - s;
    } else if (wv == 1) {
        int b0 = ln * 5, s = 0;
#pragma unroll
        for (int j = 0; j < 5; ++j) { int bb = b0 + j; if (bb < NB) s += histS[bb]; }
        int x = s;
        for (int off = 1; off < 64; off <<= 1) {
            int y = __shfl_up(x, off, 64);
            if (ln >= off) x += y;
        }
        goffS[ln] = x - s;
    }
    __syncthreads();
    for (int bb = t; bb < NB; bb += 256) {
        int g5 = bb / 5;
        int sD = goffD[g5], sS2 = goffS[g5];
        for (int k = g5 * 5; k < bb; ++k) { sD += histD[k]; sS2 += histS[k]; }
        loffD[bb] = sD; lcurD[bb] = sD;
        baseD[bb] = atomicAdd(&cursor_d[bb], histD[bb]);   // reserve global runs
        loffS[bb] = sS2; lcurS[bb] = sS2;
        baseS[bb] = atomicAdd(&cursor_s[bb], histS[bb]);
    }
    __syncthreads();
#pragma unroll
    for (int i = 0; i < 8; ++i) {
        if (myD[i] >= 0) {
            int bD = myD[i] >> 9;
            int p  = atomicAdd(&lcurD[bD], 1);
            svalD[p] = ((unsigned)(myD[i] & 511) << 18) | (unsigned)myS[i];
            sbktD[p] = (unsigned short)bD;
            int bS = myS[i] >> 9;
            int q  = atomicAdd(&lcurS[bS], 1);
            sS[q] = ((unsigned)bS << 9) | (unsigned)(myS[i] & 511);
        }
    }
    __syncthreads();
    int nval = E - e0; if (nval > EPB) nval = EPB;
    for (int p = t; p < nval; p += 256) {                // coalesced (bucket-sorted runs)
        int bD = sbktD[p];
        int wi = baseD[bD] + (p - loffD[bD]);
        if (wi < BCAP) bucket_d[(size_t)bD * BCAP + wi] = svalD[p];
        unsigned vs = sS[p];
        int bS = vs >> 9;
        int wj = baseS[bS] + (p - loffS[bS]);
        if (wj < BCAP) bucket_s[(size_t)bS * BCAP + wj] = (unsigned short)(vs & 511);
    }
}

// 2) combined finalize: blocks [0,625) build ELL from dst-buckets;
//    blocks [625, 938) count deg_out from src-buckets.
__global__ __launch_bounds__(256) void k_fin(const int* __restrict__ cursor_d,
                                             const unsigned* __restrict__ bucket_d,
                                             const int* __restrict__ cursor_s,
                                             const unsigned short* __restrict__ bucket_s,
                                             int* __restrict__ col_ell,
                                             int* __restrict__ deg_in,
                                             int* __restrict__ deg_out) {
    __shared__ char lds[256 * CAP * 4 + 2048];           // 50 KB
    int t = threadIdx.x;
    if (blockIdx.x < NDST) {
        // ---- ELL build for 256 nodes (half-bucket) ----
        int* ell = (int*)lds;                            // 256*CAP ints
        int* cnt = (int*)(lds + 256 * CAP * 4);          // 256 ints
        int blk  = blockIdx.x, b = blk >> 1, half = blk & 1;
        cnt[t] = 0;
        __syncthreads();
        int len = cursor_d[b]; if (len > BCAP) len = BCAP;
        const unsigned* p = bucket_d + (size_t)b * BCAP;
        for (int i = t; i < len; i += 256) {             // coalesced read
            unsigned e = p[i];
            int dl = e >> 18;
            if ((dl >> 8) == half) {
                int r = dl & 255;
                int pos = atomicAdd(&cnt[r], 1);         // LDS atomic
                if (pos < CAP) ell[r * CAP + pos] = (int)(e & 0x3FFFFu);
            }
        }
        __syncthreads();
        int node0 = blk << 8;
        deg_in[node0 + t] = cnt[t];
        size_t gbase = (size_t)node0 * CAP;              // 256*CAP = 12288 dwords/block
        const int4* lsrc = (const int4*)ell;
        int4* gdst = (int4*)(col_ell + gbase);
#pragma unroll
        for (int i = 0; i < 12; ++i)
            gdst[i * 256 + t] = lsrc[i * 256 + t];       // coalesced dwordx4
    } else {
        // ---- deg_out count for one 512-id src-bucket ----
        int* cnt = (int*)lds;                            // 512 ints
        int b = blockIdx.x - NDST;
        cnt[t] = 0; cnt[t + 256] = 0;
        __syncthreads();
        int len = cursor_s[b]; if (len > BCAP) len = BCAP;
        const unsigned short* p = bucket_s + (size_t)b * BCAP;
        for (int i = t; i < len; i += 256)
            atomicAdd(&cnt[p[i]], 1);
        __syncthreads();
        int n0 = b << 9;
        if (n0 + t < NTOT)       deg_out[n0 + t] = cnt[t];
        if (n0 + 256 + t < NTOT) deg_out[n0 + 256 + t] = cnt[t + 256];
    }
}

// 3) transpose inputs [SLI][FEAT][NODE] (f32) -> xs [NTOT][FEAT] (bf16), scaled by
//    rsqrt(deg_out). float4 global loads, packed 2xbf16 uint stores.
__global__ __launch_bounds__(256) void k_transpose(const float* __restrict__ in,
                                                   const int* __restrict__ deg_out,
                                                   unsigned short* __restrict__ xs) {
    __shared__ float tile[64][65];
    int sli = blockIdx.y;
    int n0  = blockIdx.x * 64;
    int t   = threadIdx.x;
    int fx  = t & 15;        // node quad
    int fr  = t >> 4;        // feat
    const float* ip = in + (size_t)sli * FEAT * NODE;
    int nq = n0 + fx * 4;
#pragma unroll
    for (int i = 0; i < 4; ++i) {
        int f = fr + i * 16;
        float4 v = {0.f, 0.f, 0.f, 0.f};
        if (nq < NODE) v = *(const float4*)(ip + (size_t)f * NODE + nq);  // coalesced 16B
        tile[f][fx * 4 + 0] = v.x;
        tile[f][fx * 4 + 1] = v.y;
        tile[f][fx * 4 + 2] = v.z;
        tile[f][fx * 4 + 3] = v.w;
    }
    __syncthreads();
    int h  = t & 31;         // feat pair: feats 2h, 2h+1
    int nr = t >> 5;
#pragma unroll
    for (int i = 0; i < 8; ++i) {
        int nl   = nr + i * 8;
        int node = n0 + nl;
        if (node < NODE) {
            int n = sli * NODE + node;
            int d = deg_out[n];
            float sc = rsqrtf(d > 0 ? (float)d : 1.f);
            unsigned lo = f2bf(tile[2 * h][nl] * sc);
            unsigned hi = f2bf(tile[2 * h + 1][nl] * sc);
            *(unsigned*)(xs + (size_t)n * 64 + 2 * h) = lo | (hi << 16);  // coalesced
        }
    }
}

// 4) fused ELL gather (8-lane x 16B, FOUR rows in flight + unroll-2 group loop
//    -> up to 8 outstanding 16B gathers/wave, zero-pad row -> no divergence)
//    + MFMA dense + bias + LeakyReLU + transposed store
__global__ __launch_bounds__(256) void k_agg_gemm(const int* __restrict__ deg_in,
                                                  const int* __restrict__ col_ell,
                                                  const unsigned short* __restrict__ xs,
                                                  const float* __restrict__ W,
                                                  const float* __restrict__ b,
                                                  float* __restrict__ out) {
    // LDS: av [64][72] bf16 @0 (9216) | wt [64][72] bf16 @9216 (9216) = 18432 B
    // otile [64][65] f32 (16640) aliases av+wt after the post-MFMA barrier.
    __shared__ char lds[18432];
    unsigned short* av = (unsigned short*)lds;
    unsigned short* wt = (unsigned short*)(lds + 9216);
    float (*otile)[65] = (float(*)[65])lds;

    int t    = threadIdx.x;
    int lane = t & 63;
    int w    = t >> 6;          // wave 0..3
    int g8   = lane >> 3;       // edge group 0..7
    int f8   = lane & 7;        // feat octet: feats 8*f8 .. 8*f8+7
    int sli  = blockIdx.y;
    int n0   = blockIdx.x * 64;

    // ---- stage Wt[out][feat] = bf16(W[feat][out]) ----
#pragma unroll
    for (int i = 0; i < 16; ++i) {
        int idx = i * 256 + t;          // idx = f*64 + o
        int f = idx >> 6, o = idx & 63;
        wt[o * 72 + f] = f2bf(W[idx]);
    }

    // ---- gather: wave w owns rows [m0, m0+16), FOUR rows in flight ----
    int m0 = w * 16;
    for (int ii = 0; ii < 16; ii += 4) {
        int dg[4], col[4];
        int gmax = 0;
#pragma unroll
        for (int r = 0; r < 4; ++r) {
            int node = n0 + m0 + ii + r;
            int n    = sli * NODE + node;
            int d    = (node < NODE) ? deg_in[n] : 0;
            dg[r] = d;
            int dc = d < CAP ? d : CAP;
            if (dc > gmax) gmax = dc;
            // pad lanes point at the zeroed xs row NTOT -> no guards inside
            col[r] = (lane < dc) ? col_ell[(size_t)n * CAP + lane] : NTOT;
        }
        float acc[4][8];
#pragma unroll
        for (int r = 0; r < 4; ++r)
#pragma unroll
            for (int k = 0; k < 8; ++k) acc[r][k] = 0.f;
        int groups = (gmax + 7) >> 3;
#pragma unroll 2
        for (int j = 0; j < groups; ++j) {
            int idx = 8 * j + g8;
            uint4 v[4];
#pragma unroll
            for (int r = 0; r < 4; ++r) {
                int s = __shfl(col[r], idx, 64);
                v[r] = *(const uint4*)(xs + (size_t)s * 64 + f8 * 8);   // 16B
            }
#pragma unroll
            for (int r = 0; r < 4; ++r) {
                acc[r][0] += __uint_as_float(v[r].x << 16);
                acc[r][1] += __uint_as_float(v[r].x & 0xffff0000u);
                acc[r][2] += __uint_as_float(v[r].y << 16);
                acc[r][3] += __uint_as_float(v[r].y & 0xffff0000u);
                acc[r][4] += __uint_as_float(v[r].z << 16);
                acc[r][5] += __uint_as_float(v[r].z & 0xffff0000u);
                acc[r][6] += __uint_as_float(v[r].w << 16);
                acc[r][7] += __uint_as_float(v[r].w & 0xffff0000u);
            }
        }
        // reduce over the 8 edge groups (lanes with same f8, stride 8)
#pragma unroll
        for (int r = 0; r < 4; ++r)
#pragma unroll
            for (int k = 0; k < 8; ++k) {
                acc[r][k] += __shfl_xor(acc[r][k], 8, 64);
                acc[r][k] += __shfl_xor(acc[r][k], 16, 64);
                acc[r][k] += __shfl_xor(acc[r][k], 32, 64);
            }
        if (g8 == 0) {    // lanes 0..7 hold feats 8*f8..8*f8+7
#pragma unroll
            for (int r = 0; r < 4; ++r) {
                float sc = rsqrtf(dg[r] > 0 ? (float)dg[r] : 1.f);
                uint4 hv;
                hv.x = (unsigned)f2bf(acc[r][0] * sc) | ((unsigned)f2bf(acc[r][1] * sc) << 16);
                hv.y = (unsigned)f2bf(acc[r][2] * sc) | ((unsigned)f2bf(acc[r][3] * sc) << 16);
                hv.z = (unsigned)f2bf(acc[r][4] * sc) | ((unsigned)f2bf(acc[r][5] * sc) << 16);
                hv.w = (unsigned)f2bf(acc[r][6] * sc) | ((unsigned)f2bf(acc[r][7] * sc) << 16);
                ((uint4*)(av + (m0 + ii + r) * 72))[f8] = hv;
            }
        }
    }

    __syncthreads();   // wt + av complete

    // ---- MFMA: O[16 nodes][64 outs] per wave, K=64 ----
    int q = lane >> 4, r16 = lane & 15;
    bf16x8 afr[2], bfr[4][2];
#pragma unroll
    for (int ks = 0; ks < 2; ++ks)
        afr[ks] = *(const bf16x8*)(av + (m0 + r16) * 72 + ks * 32 + q * 8);
#pragma unroll
    for (int nt = 0; nt < 4; ++nt)
#pragma unroll
        for (int ks = 0; ks < 2; ++ks)
            bfr[nt][ks] = *(const bf16x8*)(wt + (nt * 16 + r16) * 72 + ks * 32 + q * 8);

    f32x4 acc4[4];
#pragma unroll
    for (int nt = 0; nt < 4; ++nt) acc4[nt] = (f32x4){0.f, 0.f, 0.f, 0.f};
#pragma unroll
    for (int nt = 0; nt < 4; ++nt)
#pragma unroll
        for (int ks = 0; ks < 2; ++ks)
            acc4[nt] = __builtin_amdgcn_mfma_f32_16x16x32_bf16(afr[ks], bfr[nt][ks], acc4[nt], 0, 0, 0);
    __syncthreads();   // av/wt reads done; safe to alias otile

    // ---- epilogue: bias + LeakyReLU -> otile[out][node_local] ----
#pragma unroll
    for (int nt = 0; nt < 4; ++nt) {
        int oc = nt * 16 + r16;
        float bias = b[oc];
#pragma unroll
        for (int r = 0; r < 4; ++r) {
            float v = acc4[nt][r] + bias;
            v = v > 0.f ? v : 0.01f * v;               // LeakyReLU
            otile[oc][m0 + q * 4 + r] = v;
        }
    }
    __syncthreads();

    const size_t obase = (size_t)sli * OUTF * NODE;
#pragma unroll
    for (int i = 0; i < 16; ++i) {
        int o    = w + i * 4;
        int node = n0 + lane;
        if (node < NODE)
            out[obase + (size_t)o * NODE + node] = otile[o][lane];   // coalesced
    }
}

// ---------------------------------------------------------------------------
extern "C" void kernel_launch(void* const* d_in, const int* in_sizes, int n_in,
                              void* d_out, int out_size, void* d_ws, size_t ws_size,
                              hipStream_t stream) {
    const float* inputs = (const float*)d_in[0];
    const float* W      = (const float*)d_in[1];
    const float* b      = (const float*)d_in[2];
    const int*   src    = (const int*)d_in[3];
    const int*   dst    = (const int*)d_in[4];
    float*       out    = (float*)d_out;
    const int E = in_sizes[3];

    // Workspace (~52.5 MB): deg_out | deg_in | col_ell | R
    // R holds bucket_d+bucket_s+cursors during build; xs (+zero pad row NTOT)
    // overlays R afterwards (buckets/cursors dead once k_fin completes).
    char* ws = (char*)d_ws;
    int* deg_out = (int*)ws;
    int* deg_in  = (int*)(ws + (size_t)NTOT * 4);
    int* col_ell = (int*)(ws + (size_t)2 * NTOT * 4);
    char* R      = (char*)col_ell + (size_t)NTOT * CAP * 4;
    unsigned*       bucket_d = (unsigned*)R;                             // 11.22 MB
    unsigned short* bucket_s = (unsigned short*)(R + (size_t)NB * BCAP * 4); // 5.61 MB
    int*            cursors  = (int*)(R + (size_t)NB * BCAP * 6);
    int* cursor_d = cursors;
    int* cursor_s = cursors + NB;
    unsigned short* xs = (unsigned short*)R;   // (NTOT+1)*64 bf16 overlay (20.48 MB + pad)

    hipMemsetAsync(cursors, 0, (size_t)2 * NB * 4, stream);
    hipMemsetAsync(xs + (size_t)NTOT * 64, 0, 64 * sizeof(unsigned short), stream); // pad row

    int PB = (E + EPB - 1) / EPB;
    k_part<<<PB, 256, 0, stream>>>(src, dst, cursor_d, bucket_d, cursor_s, bucket_s, E);

    k_fin<<<NDST + NB, 256, 0, stream>>>(cursor_d, bucket_d, cursor_s, bucket_s,
                                         col_ell, deg_in, deg_out);

    dim3 tgrid((NODE + 63) / 64, SLI);
    k_transpose<<<tgrid, 256, 0, stream>>>(inputs, deg_out, xs);

    k_agg_gemm<<<tgrid, 256, 0, stream>>>(deg_in, col_ell, xs, W, b, out);
}

// Round 5
// 263.168 us; speedup vs baseline: 1.2276x; 1.0281x over previous
//
#include <hip/hip_runtime.h>
#include <hip/hip_bf16.h>

// Problem constants (fixed by the reference setup)
constexpr int SLI  = 8;
constexpr int FEAT = 64;
constexpr int NODE = 20000;
constexpr int NTOT = SLI * NODE;   // 160000
constexpr int OUTF = 64;
constexpr int CAP  = 48;           // ELL capacity; max in-deg for Poisson(16)@160k ~ 36-40
constexpr int NB   = 313;          // buckets of 512 global node ids (key = id >> 9)
constexpr int BCAP = 8960;         // bucket capacity; mean 8192, +8.5 sigma
constexpr int EPB  = 2048;         // edges per partition block (8/thread) -> 1250 blocks
constexpr int NDST = NTOT / 256;   // 625 fin_dst blocks

typedef __attribute__((ext_vector_type(8))) short bf16x8;
typedef __attribute__((ext_vector_type(4))) float f32x4;

static __device__ inline unsigned short f2bf(float x) {
    unsigned u = __float_as_uint(x);
    unsigned r = (u + 0x7fffu + ((u >> 16) & 1u)) >> 16;   // round-to-nearest-even
    return (unsigned short)r;
}

// ---------------------------------------------------------------------------
// 1) fused partition: one int4-vectorized read of (src,dst); LDS counting-sort
//    by dst-bucket (packed (dst_local<<18)|src) AND by src-bucket
//    (packed (bS<<9)|src_local). EPB=2048 -> 1250 blocks (grid 625 was the
//    occupancy ceiling at 2.4 blocks/CU); LDS ~31KB -> 5 blocks/CU fit.
__global__ __launch_bounds__(256) void k_part(const int* __restrict__ src,
                                              const int* __restrict__ dst,
                                              int* __restrict__ cursor_d,
                                              unsigned* __restrict__ bucket_d,
                                              int* __restrict__ cursor_s,
                                              unsigned short* __restrict__ bucket_s, int E) {
    __shared__ unsigned       svalD[EPB];   // 8KB
    __shared__ unsigned short sbktD[EPB];   // 4KB
    __shared__ unsigned sS[EPB];            // 8KB: (bS<<9)|src_local
    __shared__ int histD[NB], loffD[NB], lcurD[NB], baseD[NB];
    __shared__ int histS[NB], loffS[NB], lcurS[NB], baseS[NB];
    __shared__ int goffD[64], goffS[64];
    int t  = threadIdx.x;
    int e0 = blockIdx.x * EPB;
    for (int i = t; i < NB; i += 256) { histD[i] = 0; histS[i] = 0; }
    __syncthreads();
    int myS[8], myD[8];
#pragma unroll
    for (int i = 0; i < 2; ++i) {
        int j  = (e0 >> 2) + i * 256 + t;   // int4 index, coalesced 16B
        int b4 = j << 2;
        if (b4 + 3 < E) {
            int4 vs = ((const int4*)src)[j];
            int4 vd = ((const int4*)dst)[j];
            myS[4*i+0] = vs.x; myS[4*i+1] = vs.y; myS[4*i+2] = vs.z; myS[4*i+3] = vs.w;
            myD[4*i+0] = vd.x; myD[4*i+1] = vd.y; myD[4*i+2] = vd.z; myD[4*i+3] = vd.w;
        } else {
#pragma unroll
            for (int c = 0; c < 4; ++c) {
                int idx = b4 + c;
                myS[4*i+c] = (idx < E) ? src[idx] : -1;
                myD[4*i+c] = (idx < E) ? dst[idx] : -1;
            }
        }
    }
#pragma unroll
    for (int i = 0; i < 8; ++i) {
        if (myD[i] >= 0) {
            atomicAdd(&histD[myD[i] >> 9], 1);
            atomicAdd(&histS[myS[i] >> 9], 1);
        }
    }
    __syncthreads();
    // exclusive scans of histD/histS: wave 0 scans D, wave 1 scans S (64 groups of 5)
    int wv = t >> 6, ln = t & 63;
    if (wv == 0) {
        int b0 = ln * 5, s = 0;
#pragma unroll
        for (int j = 0; j < 5; ++j) { int bb = b0 + j; if (bb < NB) s += histD[bb]; }
        int x = s;
        for (int off = 1; off < 64; off <<= 1) {
            int y = __shfl_up(x, off, 64);
            if (ln >= off) x += y;
        }
        goffD[ln] = x - s;
    } else if (wv == 1) {
        int b0 = ln * 5, s = 0;
#pragma unroll
        for (int j = 0; j < 5; ++j) { int bb = b0 + j; if (bb < NB) s += histS[bb]; }
        int x = s;
        for (int off = 1; off < 64; off <<= 1) {
            int y = __shfl_up(x, off, 64);
            if (ln >= off) x += y;
        }
        goffS[ln] = x - s;
    }
    __syncthreads();
    for (int bb = t; bb < NB; bb += 256) {
        int g5 = bb / 5;
        int sD = goffD[g5], sS2 = goffS[g5];
        for (int k = g5 * 5; k < bb; ++k) { sD += histD[k]; sS2 += histS[k]; }
        loffD[bb] = sD; lcurD[bb] = sD;
        baseD[bb] = atomicAdd(&cursor_d[bb], histD[bb]);   // reserve global runs
        loffS[bb] = sS2; lcurS[bb] = sS2;
        baseS[bb] = atomicAdd(&cursor_s[bb], histS[bb]);
    }
    __syncthreads();
#pragma unroll
    for (int i = 0; i < 8; ++i) {
        if (myD[i] >= 0) {
            int bD = myD[i] >> 9;
            int p  = atomicAdd(&lcurD[bD], 1);
            svalD[p] = ((unsigned)(myD[i] & 511) << 18) | (unsigned)myS[i];
            sbktD[p] = (unsigned short)bD;
            int bS = myS[i] >> 9;
            int q  = atomicAdd(&lcurS[bS], 1);
            sS[q] = ((unsigned)bS << 9) | (unsigned)(myS[i] & 511);
        }
    }
    __syncthreads();
    int nval = E - e0; if (nval > EPB) nval = EPB;
    for (int p = t; p < nval; p += 256) {                // coalesced (bucket-sorted runs)
        int bD = sbktD[p];
        int wi = baseD[bD] + (p - loffD[bD]);
        if (wi < BCAP) bucket_d[(size_t)bD * BCAP + wi] = svalD[p];
        unsigned vs = sS[p];
        int bS = vs >> 9;
        int wj = baseS[bS] + (p - loffS[bS]);
        if (wj < BCAP) bucket_s[(size_t)bS * BCAP + wj] = (unsigned short)(vs & 511);
    }
}

// 2) combined finalize: blocks [0,625) build ELL from dst-buckets;
//    blocks [625, 938) count deg_out from src-buckets. (R0/R2-verified scalar form.)
__global__ __launch_bounds__(256) void k_fin(const int* __restrict__ cursor_d,
                                             const unsigned* __restrict__ bucket_d,
                                             const int* __restrict__ cursor_s,
                                             const unsigned short* __restrict__ bucket_s,
                                             int* __restrict__ col_ell,
                                             int* __restrict__ deg_in,
                                             int* __restrict__ deg_out) {
    __shared__ char lds[256 * CAP * 4 + 2048];           // 50 KB
    int t = threadIdx.x;
    if (blockIdx.x < NDST) {
        // ---- ELL build for 256 nodes (half-bucket) ----
        int* ell = (int*)lds;                            // 256*CAP ints
        int* cnt = (int*)(lds + 256 * CAP * 4);          // 256 ints
        int blk  = blockIdx.x, b = blk >> 1, half = blk & 1;
        cnt[t] = 0;
        __syncthreads();
        int len = cursor_d[b]; if (len > BCAP) len = BCAP;
        const unsigned* p = bucket_d + (size_t)b * BCAP;
        for (int i = t; i < len; i += 256) {             // coalesced read
            unsigned e = p[i];
            int dl = e >> 18;
            if ((dl >> 8) == half) {
                int r = dl & 255;
                int pos = atomicAdd(&cnt[r], 1);         // LDS atomic
                if (pos < CAP) ell[r * CAP + pos] = (int)(e & 0x3FFFFu);
            }
        }
        __syncthreads();
        int node0 = blk << 8;
        deg_in[node0 + t] = cnt[t];
        size_t gbase = (size_t)node0 * CAP;              // 256*CAP = 12288 dwords/block
        const int4* lsrc = (const int4*)ell;
        int4* gdst = (int4*)(col_ell + gbase);
#pragma unroll
        for (int i = 0; i < 12; ++i)
            gdst[i * 256 + t] = lsrc[i * 256 + t];       // coalesced dwordx4
    } else {
        // ---- deg_out count for one 512-id src-bucket ----
        int* cnt = (int*)lds;                            // 512 ints
        int b = blockIdx.x - NDST;
        cnt[t] = 0; cnt[t + 256] = 0;
        __syncthreads();
        int len = cursor_s[b]; if (len > BCAP) len = BCAP;
        const unsigned short* p = bucket_s + (size_t)b * BCAP;
        for (int i = t; i < len; i += 256)
            atomicAdd(&cnt[p[i]], 1);
        __syncthreads();
        int n0 = b << 9;
        if (n0 + t < NTOT)       deg_out[n0 + t] = cnt[t];
        if (n0 + 256 + t < NTOT) deg_out[n0 + 256 + t] = cnt[t + 256];
    }
}

// 3) transpose inputs [SLI][FEAT][NODE] (f32) -> xs [NTOT][FEAT] (bf16), scaled by
//    rsqrt(deg_out). float4 global loads, packed 2xbf16 uint stores.
__global__ __launch_bounds__(256) void k_transpose(const float* __restrict__ in,
                                                   const int* __restrict__ deg_out,
                                                   unsigned short* __restrict__ xs) {
    __shared__ float tile[64][65];
    int sli = blockIdx.y;
    int n0  = blockIdx.x * 64;
    int t   = threadIdx.x;
    int fx  = t & 15;        // node quad
    int fr  = t >> 4;        // feat
    const float* ip = in + (size_t)sli * FEAT * NODE;
    int nq = n0 + fx * 4;
#pragma unroll
    for (int i = 0; i < 4; ++i) {
        int f = fr + i * 16;
        float4 v = {0.f, 0.f, 0.f, 0.f};
        if (nq < NODE) v = *(const float4*)(ip + (size_t)f * NODE + nq);  // coalesced 16B
        tile[f][fx * 4 + 0] = v.x;
        tile[f][fx * 4 + 1] = v.y;
        tile[f][fx * 4 + 2] = v.z;
        tile[f][fx * 4 + 3] = v.w;
    }
    __syncthreads();
    int h  = t & 31;         // feat pair: feats 2h, 2h+1
    int nr = t >> 5;
#pragma unroll
    for (int i = 0; i < 8; ++i) {
        int nl   = nr + i * 8;
        int node = n0 + nl;
        if (node < NODE) {
            int n = sli * NODE + node;
            int d = deg_out[n];
            float sc = rsqrtf(d > 0 ? (float)d : 1.f);
            unsigned lo = f2bf(tile[2 * h][nl] * sc);
            unsigned hi = f2bf(tile[2 * h + 1][nl] * sc);
            *(unsigned*)(xs + (size_t)n * 64 + 2 * h) = lo | (hi << 16);  // coalesced
        }
    }
}

// 4) fused ELL gather (8-lane x 16B, TWO rows in flight + unroll-2 group loop,
//    zero-pad row -> no divergence) + MFMA dense + bias + LeakyReLU + store.
//    R2 lesson: 4 rows in flight cost occupancy (VGPR 56, Occ 34%) and lost.
__global__ __launch_bounds__(256) void k_agg_gemm(const int* __restrict__ deg_in,
                                                  const int* __restrict__ col_ell,
                                                  const unsigned short* __restrict__ xs,
                                                  const float* __restrict__ W,
                                                  const float* __restrict__ b,
                                                  float* __restrict__ out) {
    // LDS: av [64][72] bf16 @0 (9216) | wt [64][72] bf16 @9216 (9216) = 18432 B
    // otile [64][65] f32 (16640) aliases av+wt after the post-MFMA barrier.
    __shared__ char lds[18432];
    unsigned short* av = (unsigned short*)lds;
    unsigned short* wt = (unsigned short*)(lds + 9216);
    float (*otile)[65] = (float(*)[65])lds;

    int t    = threadIdx.x;
    int lane = t & 63;
    int w    = t >> 6;          // wave 0..3
    int g8   = lane >> 3;       // edge group 0..7
    int f8   = lane & 7;        // feat octet: feats 8*f8 .. 8*f8+7
    int sli  = blockIdx.y;
    int n0   = blockIdx.x * 64;

    // ---- stage Wt[out][feat] = bf16(W[feat][out]) ----
#pragma unroll
    for (int i = 0; i < 16; ++i) {
        int idx = i * 256 + t;          // idx = f*64 + o
        int f = idx >> 6, o = idx & 63;
        wt[o * 72 + f] = f2bf(W[idx]);
    }

    // ---- gather: wave w owns rows [m0, m0+16), two rows in flight ----
    int m0 = w * 16;
    for (int ii = 0; ii < 16; ii += 2) {
        int rowA = m0 + ii, rowB = rowA + 1;
        int nodeA = n0 + rowA, nodeB = n0 + rowB;
        int nA = sli * NODE + nodeA, nB = sli * NODE + nodeB;
        int dA = (nodeA < NODE) ? deg_in[nA] : 0;
        int dB = (nodeB < NODE) ? deg_in[nB] : 0;
        int degA = dA < CAP ? dA : CAP;
        int degB = dB < CAP ? dB : CAP;
        // pad lanes point at the zeroed xs row NTOT -> no guards in inner loop
        int cA = (lane < degA) ? col_ell[(size_t)nA * CAP + lane] : NTOT;  // coalesced
        int cB = (lane < degB) ? col_ell[(size_t)nB * CAP + lane] : NTOT;
        float accA[8] = {0,0,0,0,0,0,0,0};
        float accB[8] = {0,0,0,0,0,0,0,0};
        int gmax = degA > degB ? degA : degB;
        int groups = (gmax + 7) >> 3;
#pragma unroll 2
        for (int j = 0; j < groups; ++j) {
            int idx = 8 * j + g8;
            int sA = __shfl(cA, idx, 64);
            int sB = __shfl(cB, idx, 64);
            uint4 vA = *(const uint4*)(xs + (size_t)sA * 64 + f8 * 8);   // 16B, two rows
            uint4 vB = *(const uint4*)(xs + (size_t)sB * 64 + f8 * 8);   // in flight
            accA[0] += __uint_as_float(vA.x << 16);
            accA[1] += __uint_as_float(vA.x & 0xffff0000u);
            accA[2] += __uint_as_float(vA.y << 16);
            accA[3] += __uint_as_float(vA.y & 0xffff0000u);
            accA[4] += __uint_as_float(vA.z << 16);
            accA[5] += __uint_as_float(vA.z & 0xffff0000u);
            accA[6] += __uint_as_float(vA.w << 16);
            accA[7] += __uint_as_float(vA.w & 0xffff0000u);
            accB[0] += __uint_as_float(vB.x << 16);
            accB[1] += __uint_as_float(vB.x & 0xffff0000u);
            accB[2] += __uint_as_float(vB.y << 16);
            accB[3] += __uint_as_float(vB.y & 0xffff0000u);
            accB[4] += __uint_as_float(vB.z << 16);
            accB[5] += __uint_as_float(vB.z & 0xffff0000u);
            accB[6] += __uint_as_float(vB.w << 16);
            accB[7] += __uint_as_float(vB.w & 0xffff0000u);
        }
        // reduce over the 8 edge groups (lanes with same f8, stride 8)
#pragma unroll
        for (int k = 0; k < 8; ++k) {
            accA[k] += __shfl_xor(accA[k], 8, 64);
            accA[k] += __shfl_xor(accA[k], 16, 64);
            accA[k] += __shfl_xor(accA[k], 32, 64);
            accB[k] += __shfl_xor(accB[k], 8, 64);
            accB[k] += __shfl_xor(accB[k], 16, 64);
            accB[k] += __shfl_xor(accB[k], 32, 64);
        }
        if (g8 == 0) {    // lanes 0..7 hold feats 8*f8..8*f8+7
            float scA = rsqrtf(dA > 0 ? (float)dA : 1.f);
            float scB = rsqrtf(dB > 0 ? (float)dB : 1.f);
            uint4 hv;
            hv.x = (unsigned)f2bf(accA[0] * scA) | ((unsigned)f2bf(accA[1] * scA) << 16);
            hv.y = (unsigned)f2bf(accA[2] * scA) | ((unsigned)f2bf(accA[3] * scA) << 16);
            hv.z = (unsigned)f2bf(accA[4] * scA) | ((unsigned)f2bf(accA[5] * scA) << 16);
            hv.w = (unsigned)f2bf(accA[6] * scA) | ((unsigned)f2bf(accA[7] * scA) << 16);
            ((uint4*)(av + rowA * 72))[f8] = hv;
            hv.x = (unsigned)f2bf(accB[0] * scB) | ((unsigned)f2bf(accB[1] * scB) << 16);
            hv.y = (unsigned)f2bf(accB[2] * scB) | ((unsigned)f2bf(accB[3] * scB) << 16);
            hv.z = (unsigned)f2bf(accB[4] * scB) | ((unsigned)f2bf(accB[5] * scB) << 16);
            hv.w = (unsigned)f2bf(accB[6] * scB) | ((unsigned)f2bf(accB[7] * scB) << 16);
            ((uint4*)(av + rowB * 72))[f8] = hv;
        }
    }

    __syncthreads();   // wt + av complete

    // ---- MFMA: O[16 nodes][64 outs] per wave, K=64 ----
    int q = lane >> 4, r16 = lane & 15;
    bf16x8 afr[2], bfr[4][2];
#pragma unroll
    for (int ks = 0; ks < 2; ++ks)
        afr[ks] = *(const bf16x8*)(av + (m0 + r16) * 72 + ks * 32 + q * 8);
#pragma unroll
    for (int nt = 0; nt < 4; ++nt)
#pragma unroll
        for (int ks = 0; ks < 2; ++ks)
            bfr[nt][ks] = *(const bf16x8*)(wt + (nt * 16 + r16) * 72 + ks * 32 + q * 8);

    f32x4 acc4[4];
#pragma unroll
    for (int nt = 0; nt < 4; ++nt) acc4[nt] = (f32x4){0.f, 0.f, 0.f, 0.f};
#pragma unroll
    for (int nt = 0; nt < 4; ++nt)
#pragma unroll
        for (int ks = 0; ks < 2; ++ks)
            acc4[nt] = __builtin_amdgcn_mfma_f32_16x16x32_bf16(afr[ks], bfr[nt][ks], acc4[nt], 0, 0, 0);
    __syncthreads();   // av/wt reads done; safe to alias otile

    // ---- epilogue: bias + LeakyReLU -> otile[out][node_local] ----
#pragma unroll
    for (int nt = 0; nt < 4; ++nt) {
        int oc = nt * 16 + r16;
        float bias = b[oc];
#pragma unroll
        for (int r = 0; r < 4; ++r) {
            float v = acc4[nt][r] + bias;
            v = v > 0.f ? v : 0.01f * v;               // LeakyReLU
            otile[oc][m0 + q * 4 + r] = v;
        }
    }
    __syncthreads();

    const size_t obase = (size_t)sli * OUTF * NODE;
#pragma unroll
    for (int i = 0; i < 16; ++i) {
        int o    = w + i * 4;
        int node = n0 + lane;
        if (node < NODE)
            out[obase + (size_t)o * NODE + node] = otile[o][lane];   // coalesced
    }
}

// ---------------------------------------------------------------------------
extern "C" void kernel_launch(void* const* d_in, const int* in_sizes, int n_in,
                              void* d_out, int out_size, void* d_ws, size_t ws_size,
                              hipStream_t stream) {
    const float* inputs = (const float*)d_in[0];
    const float* W      = (const float*)d_in[1];
    const float* b      = (const float*)d_in[2];
    const int*   src    = (const int*)d_in[3];
    const int*   dst    = (const int*)d_in[4];
    float*       out    = (float*)d_out;
    const int E = in_sizes[3];

    // Workspace (~52.5 MB): deg_out | deg_in | col_ell | R
    // R holds bucket_d+bucket_s+cursors during build; xs (+zero pad row NTOT)
    // overlays R afterwards (buckets/cursors dead once k_fin completes).
    char* ws = (char*)d_ws;
    int* deg_out = (int*)ws;
    int* deg_in  = (int*)(ws + (size_t)NTOT * 4);
    int* col_ell = (int*)(ws + (size_t)2 * NTOT * 4);
    char* R      = (char*)col_ell + (size_t)NTOT * CAP * 4;
    unsigned*       bucket_d = (unsigned*)R;                             // 11.22 MB
    unsigned short* bucket_s = (unsigned short*)(R + (size_t)NB * BCAP * 4); // 5.61 MB
    int*            cursors  = (int*)(R + (size_t)NB * BCAP * 6);
    int* cursor_d = cursors;
    int* cursor_s = cursors + NB;
    unsigned short* xs = (unsigned short*)R;   // (NTOT+1)*64 bf16 overlay (20.48 MB + pad)

    hipMemsetAsync(cursors, 0, (size_t)2 * NB * 4, stream);
    hipMemsetAsync(xs + (size_t)NTOT * 64, 0, 64 * sizeof(unsigned short), stream); // pad row

    int PB = (E + EPB - 1) / EPB;
    k_part<<<PB, 256, 0, stream>>>(src, dst, cursor_d, bucket_d, cursor_s, bucket_s, E);

    k_fin<<<NDST + NB, 256, 0, stream>>>(cursor_d, bucket_d, cursor_s, bucket_s,
                                         col_ell, deg_in, deg_out);

    dim3 tgrid((NODE + 63) / 64, SLI);
    k_transpose<<<tgrid, 256, 0, stream>>>(inputs, deg_out, xs);

    k_agg_gemm<<<tgrid, 256, 0, stream>>>(deg_in, col_ell, xs, W, b, out);
}

// Round 6
// 243.506 us; speedup vs baseline: 1.3267x; 1.0807x over previous
//
#include <hip/hip_runtime.h>
#include <hip/hip_bf16.h>

// Problem constants (fixed by the reference setup)
constexpr int SLI  = 8;
constexpr int FEAT = 64;
constexpr int NODE = 20000;
constexpr int NTOT = SLI * NODE;   // 160000
constexpr int OUTF = 64;
constexpr int CAP  = 48;           // ELL capacity; max in-deg for Poisson(16)@160k ~ 36-40
constexpr int NBD  = 625;          // dst buckets of 256 ids (key = id >> 8)
constexpr int NBS  = 313;          // src buckets of 512 ids (key = id >> 9)
constexpr int BCAPD = 4864;        // dst bucket capacity; mean 4096, +12 sigma
constexpr int BCAPS = 8960;        // src bucket capacity; mean 8192, +8.5 sigma
constexpr int EPB  = 4096;         // edges per partition block (16/thread) -> 625 blocks
constexpr int NDST = NTOT / 256;   // 625 fin ELL blocks (one 256-id bucket each)

typedef __attribute__((ext_vector_type(8))) short bf16x8;
typedef __attribute__((ext_vector_type(4))) float f32x4;

static __device__ inline unsigned short f2bf(float x) {
    unsigned u = __float_as_uint(x);
    unsigned r = (u + 0x7fffu + ((u >> 16) & 1u)) >> 16;   // round-to-nearest-even
    return (unsigned short)r;
}

// ---------------------------------------------------------------------------
// 1) fused partition @ EPB 4096 (R5 lesson: EPB 2048 cost +21us in per-block
//    fixed overhead). int4-vectorized edge loads; LDS counting-sort by
//    256-id dst-bucket (packed (dst_local<<18)|src, dst_local 8b + src 18b)
//    and by 512-id src-bucket (packed (bS<<9)|src_local).
__global__ __launch_bounds__(256) void k_part(const int* __restrict__ src,
                                              const int* __restrict__ dst,
                                              int* __restrict__ cursor_d,
                                              unsigned* __restrict__ bucket_d,
                                              int* __restrict__ cursor_s,
                                              unsigned short* __restrict__ bucket_s, int E) {
    __shared__ unsigned       svalD[EPB];   // 16KB
    __shared__ unsigned short sbktD[EPB];   // 8KB
    __shared__ unsigned sS[EPB];            // 16KB: (bS<<9)|src_local
    __shared__ int histD[NBD], loffD[NBD], lcurD[NBD], baseD[NBD];  // 10KB
    __shared__ int histS[NBS], loffS[NBS], lcurS[NBS], baseS[NBS];  // 5KB
    __shared__ int goffD[64], goffS[64];    // total ~56.5KB -> 2 blocks/CU
    int t  = threadIdx.x;
    int e0 = blockIdx.x * EPB;
    for (int i = t; i < NBD; i += 256) histD[i] = 0;
    for (int i = t; i < NBS; i += 256) histS[i] = 0;
    __syncthreads();
    int myS[16], myD[16];
#pragma unroll
    for (int i = 0; i < 4; ++i) {
        int j  = (e0 >> 2) + i * 256 + t;   // int4 index, coalesced 16B
        int b4 = j << 2;
        if (b4 + 3 < E) {
            int4 vs = ((const int4*)src)[j];
            int4 vd = ((const int4*)dst)[j];
            myS[4*i+0] = vs.x; myS[4*i+1] = vs.y; myS[4*i+2] = vs.z; myS[4*i+3] = vs.w;
            myD[4*i+0] = vd.x; myD[4*i+1] = vd.y; myD[4*i+2] = vd.z; myD[4*i+3] = vd.w;
        } else {
#pragma unroll
            for (int c = 0; c < 4; ++c) {
                int idx = b4 + c;
                myS[4*i+c] = (idx < E) ? src[idx] : -1;
                myD[4*i+c] = (idx < E) ? dst[idx] : -1;
            }
        }
    }
#pragma unroll
    for (int i = 0; i < 16; ++i) {
        if (myD[i] >= 0) {
            atomicAdd(&histD[myD[i] >> 8], 1);
            atomicAdd(&histS[myS[i] >> 9], 1);
        }
    }
    __syncthreads();
    // exclusive scans: wave 0 scans D (10 bins/lane), wave 1 scans S (5 bins/lane)
    int wv = t >> 6, ln = t & 63;
    if (wv == 0) {
        int b0 = ln * 10, s = 0;
#pragma unroll
        for (int j = 0; j < 10; ++j) { int bb = b0 + j; if (bb < NBD) s += histD[bb]; }
        int x = s;
        for (int off = 1; off < 64; off <<= 1) {
            int y = __shfl_up(x, off, 64);
            if (ln >= off) x += y;
        }
        goffD[ln] = x - s;
    } else if (wv == 1) {
        int b0 = ln * 5, s = 0;
#pragma unroll
        for (int j = 0; j < 5; ++j) { int bb = b0 + j; if (bb < NBS) s += histS[bb]; }
        int x = s;
        for (int off = 1; off < 64; off <<= 1) {
            int y = __shfl_up(x, off, 64);
            if (ln >= off) x += y;
        }
        goffS[ln] = x - s;
    }
    __syncthreads();
    for (int bb = t; bb < NBD; bb += 256) {
        int g = bb / 10;
        int sD = goffD[g];
        for (int k = g * 10; k < bb; ++k) sD += histD[k];
        loffD[bb] = sD; lcurD[bb] = sD;
        baseD[bb] = atomicAdd(&cursor_d[bb], histD[bb]);   // reserve global run
    }
    for (int bb = t; bb < NBS; bb += 256) {
        int g = bb / 5;
        int sS2 = goffS[g];
        for (int k = g * 5; k < bb; ++k) sS2 += histS[k];
        loffS[bb] = sS2; lcurS[bb] = sS2;
        baseS[bb] = atomicAdd(&cursor_s[bb], histS[bb]);
    }
    __syncthreads();
#pragma unroll
    for (int i = 0; i < 16; ++i) {
        if (myD[i] >= 0) {
            int bD = myD[i] >> 8;
            int p  = atomicAdd(&lcurD[bD], 1);
            svalD[p] = ((unsigned)(myD[i] & 255) << 18) | (unsigned)myS[i];
            sbktD[p] = (unsigned short)bD;
            int bS = myS[i] >> 9;
            int q  = atomicAdd(&lcurS[bS], 1);
            sS[q] = ((unsigned)bS << 9) | (unsigned)(myS[i] & 511);
        }
    }
    __syncthreads();
    int nval = E - e0; if (nval > EPB) nval = EPB;
    for (int p = t; p < nval; p += 256) {                // coalesced (bucket-sorted runs)
        int bD = sbktD[p];
        int wi = baseD[bD] + (p - loffD[bD]);
        if (wi < BCAPD) bucket_d[(size_t)bD * BCAPD + wi] = svalD[p];
        unsigned vs = sS[p];
        int bS = vs >> 9;
        int wj = baseS[bS] + (p - loffS[bS]);
        if (wj < BCAPS) bucket_s[(size_t)bS * BCAPS + wj] = (unsigned short)(vs & 511);
    }
}

// 2) combined finalize: blocks [0,625) build ELL, one FULL 256-id dst-bucket
//    per block (no half-discard: 16 scan iters vs 32, zero wasted reads);
//    blocks [625, 938) count deg_out from 512-id src-buckets.
__global__ __launch_bounds__(256) void k_fin(const int* __restrict__ cursor_d,
                                             const unsigned* __restrict__ bucket_d,
                                             const int* __restrict__ cursor_s,
                                             const unsigned short* __restrict__ bucket_s,
                                             int* __restrict__ col_ell,
                                             int* __restrict__ deg_in,
                                             int* __restrict__ deg_out) {
    __shared__ char lds[256 * CAP * 4 + 2048];           // 50 KB
    int t = threadIdx.x;
    if (blockIdx.x < NDST) {
        // ---- ELL build for 256 nodes (one full bucket) ----
        int* ell = (int*)lds;                            // 256*CAP ints
        int* cnt = (int*)(lds + 256 * CAP * 4);          // 256 ints
        int b = blockIdx.x;
        cnt[t] = 0;
        __syncthreads();
        int len = cursor_d[b]; if (len > BCAPD) len = BCAPD;
        const unsigned* p = bucket_d + (size_t)b * BCAPD;
        for (int i = t; i < len; i += 256) {             // coalesced read, no discard
            unsigned e = p[i];
            int r = (e >> 18) & 255;                     // dst_local
            int pos = atomicAdd(&cnt[r], 1);             // LDS atomic
            if (pos < CAP) ell[r * CAP + pos] = (int)(e & 0x3FFFFu);
        }
        __syncthreads();
        int node0 = b << 8;
        deg_in[node0 + t] = cnt[t];
        size_t gbase = (size_t)node0 * CAP;              // 256*CAP = 12288 dwords/block
        const int4* lsrc = (const int4*)ell;
        int4* gdst = (int4*)(col_ell + gbase);
#pragma unroll
        for (int i = 0; i < 12; ++i)
            gdst[i * 256 + t] = lsrc[i * 256 + t];       // coalesced dwordx4
    } else {
        // ---- deg_out count for one 512-id src-bucket ----
        int* cnt = (int*)lds;                            // 512 ints
        int b = blockIdx.x - NDST;
        cnt[t] = 0; cnt[t + 256] = 0;
        __syncthreads();
        int len = cursor_s[b]; if (len > BCAPS) len = BCAPS;
        const unsigned short* p = bucket_s + (size_t)b * BCAPS;
        for (int i = t; i < len; i += 256)
            atomicAdd(&cnt[p[i]], 1);
        __syncthreads();
        int n0 = b << 9;
        if (n0 + t < NTOT)       deg_out[n0 + t] = cnt[t];
        if (n0 + 256 + t < NTOT) deg_out[n0 + 256 + t] = cnt[t + 256];
    }
}

// 3) transpose inputs [SLI][FEAT][NODE] (f32) -> xs [NTOT][FEAT] (bf16), scaled by
//    rsqrt(deg_out). float4 global loads, packed 2xbf16 uint stores.
__global__ __launch_bounds__(256) void k_transpose(const float* __restrict__ in,
                                                   const int* __restrict__ deg_out,
                                                   unsigned short* __restrict__ xs) {
    __shared__ float tile[64][65];
    int sli = blockIdx.y;
    int n0  = blockIdx.x * 64;
    int t   = threadIdx.x;
    int fx  = t & 15;        // node quad
    int fr  = t >> 4;        // feat
    const float* ip = in + (size_t)sli * FEAT * NODE;
    int nq = n0 + fx * 4;
#pragma unroll
    for (int i = 0; i < 4; ++i) {
        int f = fr + i * 16;
        float4 v = {0.f, 0.f, 0.f, 0.f};
        if (nq < NODE) v = *(const float4*)(ip + (size_t)f * NODE + nq);  // coalesced 16B
        tile[f][fx * 4 + 0] = v.x;
        tile[f][fx * 4 + 1] = v.y;
        tile[f][fx * 4 + 2] = v.z;
        tile[f][fx * 4 + 3] = v.w;
    }
    __syncthreads();
    int h  = t & 31;         // feat pair: feats 2h, 2h+1
    int nr = t >> 5;
#pragma unroll
    for (int i = 0; i < 8; ++i) {
        int nl   = nr + i * 8;
        int node = n0 + nl;
        if (node < NODE) {
            int n = sli * NODE + node;
            int d = deg_out[n];
            float sc = rsqrtf(d > 0 ? (float)d : 1.f);
            unsigned lo = f2bf(tile[2 * h][nl] * sc);
            unsigned hi = f2bf(tile[2 * h + 1][nl] * sc);
            *(unsigned*)(xs + (size_t)n * 64 + 2 * h) = lo | (hi << 16);  // coalesced
        }
    }
}

// 4) fused ELL gather (8-lane x 16B, two rows in flight, zero-pad row -> no
//    divergence) + MFMA dense + bias + LeakyReLU + transposed store.
//    Verified at 73.5us / VGPR 36 / Occ 55% (R0+R5); gather runs at the
//    ~4.5 TB/s random-128B L2/L3 ceiling -> leave untouched.
__global__ __launch_bounds__(256) void k_agg_gemm(const int* __restrict__ deg_in,
                                                  const int* __restrict__ col_ell,
                                                  const unsigned short* __restrict__ xs,
                                                  const float* __restrict__ W,
                                                  const float* __restrict__ b,
                                                  float* __restrict__ out) {
    // LDS: av [64][72] bf16 @0 (9216) | wt [64][72] bf16 @9216 (9216) = 18432 B
    // otile [64][65] f32 (16640) aliases av+wt after the post-MFMA barrier.
    __shared__ char lds[18432];
    unsigned short* av = (unsigned short*)lds;
    unsigned short* wt = (unsigned short*)(lds + 9216);
    float (*otile)[65] = (float(*)[65])lds;

    int t    = threadIdx.x;
    int lane = t & 63;
    int w    = t >> 6;          // wave 0..3
    int g8   = lane >> 3;       // edge group 0..7
    int f8   = lane & 7;        // feat octet: feats 8*f8 .. 8*f8+7
    int sli  = blockIdx.y;
    int n0   = blockIdx.x * 64;

    // ---- stage Wt[out][feat] = bf16(W[feat][out]) ----
#pragma unroll
    for (int i = 0; i < 16; ++i) {
        int idx = i * 256 + t;          // idx = f*64 + o
        int f = idx >> 6, o = idx & 63;
        wt[o * 72 + f] = f2bf(W[idx]);
    }

    // ---- gather: wave w owns rows [m0, m0+16), two rows in flight ----
    int m0 = w * 16;
    for (int ii = 0; ii < 16; ii += 2) {
        int rowA = m0 + ii, rowB = rowA + 1;
        int nodeA = n0 + rowA, nodeB = n0 + rowB;
        int nA = sli * NODE + nodeA, nB = sli * NODE + nodeB;
        int dA = (nodeA < NODE) ? deg_in[nA] : 0;
        int dB = (nodeB < NODE) ? deg_in[nB] : 0;
        int degA = dA < CAP ? dA : CAP;
        int degB = dB < CAP ? dB : CAP;
        // pad lanes point at the zeroed xs row NTOT -> no guards in inner loop
        int cA = (lane < degA) ? col_ell[(size_t)nA * CAP + lane] : NTOT;  // coalesced
        int cB = (lane < degB) ? col_ell[(size_t)nB * CAP + lane] : NTOT;
        float accA[8] = {0,0,0,0,0,0,0,0};
        float accB[8] = {0,0,0,0,0,0,0,0};
        int gmax = degA > degB ? degA : degB;
        int groups = (gmax + 7) >> 3;
#pragma unroll 2
        for (int j = 0; j < groups; ++j) {
            int idx = 8 * j + g8;
            int sA = __shfl(cA, idx, 64);
            int sB = __shfl(cB, idx, 64);
            uint4 vA = *(const uint4*)(xs + (size_t)sA * 64 + f8 * 8);   // 16B, two rows
            uint4 vB = *(const uint4*)(xs + (size_t)sB * 64 + f8 * 8);   // in flight
            accA[0] += __uint_as_float(vA.x << 16);
            accA[1] += __uint_as_float(vA.x & 0xffff0000u);
            accA[2] += __uint_as_float(vA.y << 16);
            accA[3] += __uint_as_float(vA.y & 0xffff0000u);
            accA[4] += __uint_as_float(vA.z << 16);
            accA[5] += __uint_as_float(vA.z & 0xffff0000u);
            accA[6] += __uint_as_float(vA.w << 16);
            accA[7] += __uint_as_float(vA.w & 0xffff0000u);
            accB[0] += __uint_as_float(vB.x << 16);
            accB[1] += __uint_as_float(vB.x & 0xffff0000u);
            accB[2] += __uint_as_float(vB.y << 16);
            accB[3] += __uint_as_float(vB.y & 0xffff0000u);
            accB[4] += __uint_as_float(vB.z << 16);
            accB[5] += __uint_as_float(vB.z & 0xffff0000u);
            accB[6] += __uint_as_float(vB.w << 16);
            accB[7] += __uint_as_float(vB.w & 0xffff0000u);
        }
        // reduce over the 8 edge groups (lanes with same f8, stride 8)
#pragma unroll
        for (int k = 0; k < 8; ++k) {
            accA[k] += __shfl_xor(accA[k], 8, 64);
            accA[k] += __shfl_xor(accA[k], 16, 64);
            accA[k] += __shfl_xor(accA[k], 32, 64);
            accB[k] += __shfl_xor(accB[k], 8, 64);
            accB[k] += __shfl_xor(accB[k], 16, 64);
            accB[k] += __shfl_xor(accB[k], 32, 64);
        }
        if (g8 == 0) {    // lanes 0..7 hold feats 8*f8..8*f8+7
            float scA = rsqrtf(dA > 0 ? (float)dA : 1.f);
            float scB = rsqrtf(dB > 0 ? (float)dB : 1.f);
            uint4 hv;
            hv.x = (unsigned)f2bf(accA[0] * scA) | ((unsigned)f2bf(accA[1] * scA) << 16);
            hv.y = (unsigned)f2bf(accA[2] * scA) | ((unsigned)f2bf(accA[3] * scA) << 16);
            hv.z = (unsigned)f2bf(accA[4] * scA) | ((unsigned)f2bf(accA[5] * scA) << 16);
            hv.w = (unsigned)f2bf(accA[6] * scA) | ((unsigned)f2bf(accA[7] * scA) << 16);
            ((uint4*)(av + rowA * 72))[f8] = hv;
            hv.x = (unsigned)f2bf(accB[0] * scB) | ((unsigned)f2bf(accB[1] * scB) << 16);
            hv.y = (unsigned)f2bf(accB[2] * scB) | ((unsigned)f2bf(accB[3] * scB) << 16);
            hv.z = (unsigned)f2bf(accB[4] * scB) | ((unsigned)f2bf(accB[5] * scB) << 16);
            hv.w = (unsigned)f2bf(accB[6] * scB) | ((unsigned)f2bf(accB[7] * scB) << 16);
            ((uint4*)(av + rowB * 72))[f8] = hv;
        }
    }

    __syncthreads();   // wt + av complete

    // ---- MFMA: O[16 nodes][64 outs] per wave, K=64 ----
    int q = lane >> 4, r16 = lane & 15;
    bf16x8 afr[2], bfr[4][2];
#pragma unroll
    for (int ks = 0; ks < 2; ++ks)
        afr[ks] = *(const bf16x8*)(av + (m0 + r16) * 72 + ks * 32 + q * 8);
#pragma unroll
    for (int nt = 0; nt < 4; ++nt)
#pragma unroll
        for (int ks = 0; ks < 2; ++ks)
            bfr[nt][ks] = *(const bf16x8*)(wt + (nt * 16 + r16) * 72 + ks * 32 + q * 8);

    f32x4 acc4[4];
#pragma unroll
    for (int nt = 0; nt < 4; ++nt) acc4[nt] = (f32x4){0.f, 0.f, 0.f, 0.f};
#pragma unroll
    for (int nt = 0; nt < 4; ++nt)
#pragma unroll
        for (int ks = 0; ks < 2; ++ks)
            acc4[nt] = __builtin_amdgcn_mfma_f32_16x16x32_bf16(afr[ks], bfr[nt][ks], acc4[nt], 0, 0, 0);
    __syncthreads();   // av/wt reads done; safe to alias otile

    // ---- epilogue: bias + LeakyReLU -> otile[out][node_local] ----
#pragma unroll
    for (int nt = 0; nt < 4; ++nt) {
        int oc = nt * 16 + r16;
        float bias = b[oc];
#pragma unroll
        for (int r = 0; r < 4; ++r) {
            float v = acc4[nt][r] + bias;
            v = v > 0.f ? v : 0.01f * v;               // LeakyReLU
            otile[oc][m0 + q * 4 + r] = v;
        }
    }
    __syncthreads();

    const size_t obase = (size_t)sli * OUTF * NODE;
#pragma unroll
    for (int i = 0; i < 16; ++i) {
        int o    = w + i * 4;
        int node = n0 + lane;
        if (node < NODE)
            out[obase + (size_t)o * NODE + node] = otile[o][lane];   // coalesced
    }
}

// ---------------------------------------------------------------------------
extern "C" void kernel_launch(void* const* d_in, const int* in_sizes, int n_in,
                              void* d_out, int out_size, void* d_ws, size_t ws_size,
                              hipStream_t stream) {
    const float* inputs = (const float*)d_in[0];
    const float* W      = (const float*)d_in[1];
    const float* b      = (const float*)d_in[2];
    const int*   src    = (const int*)d_in[3];
    const int*   dst    = (const int*)d_in[4];
    float*       out    = (float*)d_out;
    const int E = in_sizes[3];

    // Workspace (~52.5 MB): deg_out | deg_in | col_ell | R
    // R holds bucket_d (12.16MB) + bucket_s (5.61MB) + cursors during build;
    // xs (+zero pad row NTOT) overlays R afterwards (20.48MB; build structs dead).
    char* ws = (char*)d_ws;
    int* deg_out = (int*)ws;
    int* deg_in  = (int*)(ws + (size_t)NTOT * 4);
    int* col_ell = (int*)(ws + (size_t)2 * NTOT * 4);
    char* R      = (char*)col_ell + (size_t)NTOT * CAP * 4;
    unsigned*       bucket_d = (unsigned*)R;                               // 12.16 MB
    unsigned short* bucket_s = (unsigned short*)(R + (size_t)NBD * BCAPD * 4); // 5.61 MB
    int*            cursors  = (int*)(R + (size_t)NBD * BCAPD * 4 + (size_t)NBS * BCAPS * 2);
    int* cursor_d = cursors;            // NBD ints
    int* cursor_s = cursors + NBD;      // NBS ints
    unsigned short* xs = (unsigned short*)R;   // (NTOT+1)*64 bf16 overlay (20.48 MB + pad)

    hipMemsetAsync(cursors, 0, (size_t)(NBD + NBS) * 4, stream);
    hipMemsetAsync(xs + (size_t)NTOT * 64, 0, 64 * sizeof(unsigned short), stream); // pad row

    int PB = (E + EPB - 1) / EPB;
    k_part<<<PB, 256, 0, stream>>>(src, dst, cursor_d, bucket_d, cursor_s, bucket_s, E);

    k_fin<<<NDST + NBS, 256, 0, stream>>>(cursor_d, bucket_d, cursor_s, bucket_s,
                                          col_ell, deg_in, deg_out);

    dim3 tgrid((NODE + 63) / 64, SLI);
    k_transpose<<<tgrid, 256, 0, stream>>>(inputs, deg_out, xs);

    k_agg_gemm<<<tgrid, 256, 0, stream>>>(deg_in, col_ell, xs, W, b, out);
}

// Round 7
// 223.308 us; speedup vs baseline: 1.4467x; 1.0904x over previous
//
#include <hip/hip_runtime.h>
#include <hip/hip_bf16.h>

// Problem constants (fixed by the reference setup)
constexpr int SLI  = 8;
constexpr int FEAT = 64;
constexpr int NODE = 20000;
constexpr int NTOT = SLI * NODE;   // 160000
constexpr int OUTF = 64;
constexpr int CAP  = 48;           // ELL capacity; max in-deg for Poisson(16)@160k ~ 36-40
constexpr int NBD  = 625;          // dst buckets of 256 ids (key = id >> 8)
constexpr int NBS  = 313;          // src buckets of 512 ids (key = id >> 9)
constexpr int BCAPD = 4864;        // dst bucket capacity; mean 4096, +12 sigma
constexpr int BCAPS = 8960;        // src bucket capacity; mean 8192, +8.5 sigma
constexpr int EPB  = 4096;         // edges per partition block (16/thread) -> 625 blocks
constexpr int NDST = NTOT / 256;   // 625 fin ELL blocks (one 256-id bucket each)

typedef __attribute__((ext_vector_type(8))) short bf16x8;
typedef __attribute__((ext_vector_type(4))) float f32x4;

static __device__ inline unsigned short f2bf(float x) {
    unsigned u = __float_as_uint(x);
    unsigned r = (u + 0x7fffu + ((u >> 16) & 1u)) >> 16;   // round-to-nearest-even
    return (unsigned short)r;
}

// ---------------------------------------------------------------------------
// 1) fused partition @ EPB 4096. int4 edge loads; LDS counting-sort by 256-id
//    dst-bucket and 512-id src-bucket.
//    R7: cursor reservations (938 contended global atomicAdd-with-return per
//    block, all blocks on the same 938 counters) are ISSUED early into
//    registers and COMMITTED to LDS only after placement; the intervening
//    barriers are raw s_barrier + lgkmcnt(0) (no vmcnt drain) so the atomic
//    returns stay in flight under ~10us of scan/placement work.
//    loff arrays dropped (loff = lcur - hist) -> LDS 51.75KB -> 3 blocks/CU.
__global__ __launch_bounds__(256) void k_part(const int* __restrict__ src,
                                              const int* __restrict__ dst,
                                              int* __restrict__ cursor_d,
                                              unsigned* __restrict__ bucket_d,
                                              int* __restrict__ cursor_s,
                                              unsigned short* __restrict__ bucket_s, int E) {
    __shared__ unsigned       svalD[EPB];   // 16KB
    __shared__ unsigned short sbktD[EPB];   // 8KB
    __shared__ unsigned sS[EPB];            // 16KB: (bS<<9)|src_local
    __shared__ int histD[NBD], lcurD[NBD], baseD[NBD];  // 7.5KB
    __shared__ int histS[NBS], lcurS[NBS], baseS[NBS];  // 3.75KB
    __shared__ int goffD[64], goffS[64];    // total ~51.75KB -> 3 blocks/CU
    int t  = threadIdx.x;
    int e0 = blockIdx.x * EPB;
    for (int i = t; i < NBD; i += 256) histD[i] = 0;
    for (int i = t; i < NBS; i += 256) histS[i] = 0;
    __syncthreads();
    int myS[16], myD[16];
#pragma unroll
    for (int i = 0; i < 4; ++i) {
        int j  = (e0 >> 2) + i * 256 + t;   // int4 index, coalesced 16B
        int b4 = j << 2;
        if (b4 + 3 < E) {
            int4 vs = ((const int4*)src)[j];
            int4 vd = ((const int4*)dst)[j];
            myS[4*i+0] = vs.x; myS[4*i+1] = vs.y; myS[4*i+2] = vs.z; myS[4*i+3] = vs.w;
            myD[4*i+0] = vd.x; myD[4*i+1] = vd.y; myD[4*i+2] = vd.z; myD[4*i+3] = vd.w;
        } else {
#pragma unroll
            for (int c = 0; c < 4; ++c) {
                int idx = b4 + c;
                myS[4*i+c] = (idx < E) ? src[idx] : -1;
                myD[4*i+c] = (idx < E) ? dst[idx] : -1;
            }
        }
    }
#pragma unroll
    for (int i = 0; i < 16; ++i) {
        if (myD[i] >= 0) {
            atomicAdd(&histD[myD[i] >> 8], 1);
            atomicAdd(&histS[myS[i] >> 9], 1);
        }
    }
    __syncthreads();
    // ---- issue cursor reservations EARLY; results stay in registers ----
    int rbD[3], rbS[2];
#pragma unroll
    for (int i = 0; i < 3; ++i) {
        int bb = t + i * 256;
        rbD[i] = (bb < NBD) ? atomicAdd(&cursor_d[bb], histD[bb]) : 0;
    }
#pragma unroll
    for (int i = 0; i < 2; ++i) {
        int bb = t + i * 256;
        rbS[i] = (bb < NBS) ? atomicAdd(&cursor_s[bb], histS[bb]) : 0;
    }
    // exclusive scans: wave 0 scans D (10 bins/lane), wave 1 scans S (5 bins/lane)
    int wv = t >> 6, ln = t & 63;
    if (wv == 0) {
        int b0 = ln * 10, s = 0;
#pragma unroll
        for (int j = 0; j < 10; ++j) { int bb = b0 + j; if (bb < NBD) s += histD[bb]; }
        int x = s;
        for (int off = 1; off < 64; off <<= 1) {
            int y = __shfl_up(x, off, 64);
            if (ln >= off) x += y;
        }
        goffD[ln] = x - s;
    } else if (wv == 1) {
        int b0 = ln * 5, s = 0;
#pragma unroll
        for (int j = 0; j < 5; ++j) { int bb = b0 + j; if (bb < NBS) s += histS[bb]; }
        int x = s;
        for (int off = 1; off < 64; off <<= 1) {
            int y = __shfl_up(x, off, 64);
            if (ln >= off) x += y;
        }
        goffS[ln] = x - s;
    }
    // barrier WITHOUT vmcnt drain (atomic returns stay in flight)
    asm volatile("s_waitcnt lgkmcnt(0)\n\ts_barrier" ::: "memory");
    for (int bb = t; bb < NBD; bb += 256) {
        int g = bb / 10;
        int sD = goffD[g];
        for (int k = g * 10; k < bb; ++k) sD += histD[k];
        lcurD[bb] = sD;
    }
    for (int bb = t; bb < NBS; bb += 256) {
        int g = bb / 5;
        int sS2 = goffS[g];
        for (int k = g * 5; k < bb; ++k) sS2 += histS[k];
        lcurS[bb] = sS2;
    }
    asm volatile("s_waitcnt lgkmcnt(0)\n\ts_barrier" ::: "memory");
#pragma unroll
    for (int i = 0; i < 16; ++i) {
        if (myD[i] >= 0) {
            int bD = myD[i] >> 8;
            int p  = atomicAdd(&lcurD[bD], 1);
            svalD[p] = ((unsigned)(myD[i] & 255) << 18) | (unsigned)myS[i];
            sbktD[p] = (unsigned short)bD;
            int bS = myS[i] >> 9;
            int q  = atomicAdd(&lcurS[bS], 1);
            sS[q] = ((unsigned)bS << 9) | (unsigned)(myS[i] & 511);
        }
    }
    // ---- commit reservations (first true wait on the atomic returns) ----
#pragma unroll
    for (int i = 0; i < 3; ++i) { int bb = t + i * 256; if (bb < NBD) baseD[bb] = rbD[i]; }
#pragma unroll
    for (int i = 0; i < 2; ++i) { int bb = t + i * 256; if (bb < NBS) baseS[bb] = rbS[i]; }
    __syncthreads();
    int nval = E - e0; if (nval > EPB) nval = EPB;
    for (int p = t; p < nval; p += 256) {                // coalesced (bucket-sorted runs)
        int bD = sbktD[p];
        int wi = baseD[bD] + (p - (lcurD[bD] - histD[bD]));   // loff = lcur - hist
        if (wi < BCAPD) bucket_d[(size_t)bD * BCAPD + wi] = svalD[p];
        unsigned vs = sS[p];
        int bS = vs >> 9;
        int wj = baseS[bS] + (p - (lcurS[bS] - histS[bS]));
        if (wj < BCAPS) bucket_s[(size_t)bS * BCAPS + wj] = (unsigned short)(vs & 511);
    }
}

// 2) combined finalize @ 512 threads (R7: halves scan iters, 24 waves/CU vs 12):
//    blocks [0,625) build ELL from one full 256-id dst-bucket;
//    blocks [625, 938) count deg_out from one 512-id src-bucket.
__global__ __launch_bounds__(512) void k_fin(const int* __restrict__ cursor_d,
                                             const unsigned* __restrict__ bucket_d,
                                             const int* __restrict__ cursor_s,
                                             const unsigned short* __restrict__ bucket_s,
                                             int* __restrict__ col_ell,
                                             int* __restrict__ deg_in,
                                             int* __restrict__ deg_out) {
    __shared__ char lds[256 * CAP * 4 + 2048];           // 50 KB -> 3 blocks/CU
    int t = threadIdx.x;
    if (blockIdx.x < NDST) {
        // ---- ELL build for 256 nodes (one full bucket) ----
        int* ell = (int*)lds;                            // 256*CAP ints
        int* cnt = (int*)(lds + 256 * CAP * 4);          // 256 ints
        int b = blockIdx.x;
        if (t < 256) cnt[t] = 0;
        __syncthreads();
        int len = cursor_d[b]; if (len > BCAPD) len = BCAPD;
        const unsigned* p = bucket_d + (size_t)b * BCAPD;
        for (int i = t; i < len; i += 512) {             // coalesced read, no discard
            unsigned e = p[i];
            int r = (e >> 18) & 255;                     // dst_local
            int pos = atomicAdd(&cnt[r], 1);             // LDS atomic
            if (pos < CAP) ell[r * CAP + pos] = (int)(e & 0x3FFFFu);
        }
        __syncthreads();
        int node0 = b << 8;
        if (t < 256) deg_in[node0 + t] = cnt[t];
        size_t gbase = (size_t)node0 * CAP;              // 3072 int4s / 512 = 6 iters
        const int4* lsrc = (const int4*)ell;
        int4* gdst = (int4*)(col_ell + gbase);
#pragma unroll
        for (int i = 0; i < 6; ++i)
            gdst[i * 512 + t] = lsrc[i * 512 + t];       // coalesced dwordx4
    } else {
        // ---- deg_out count for one 512-id src-bucket ----
        int* cnt = (int*)lds;                            // 512 ints
        int b = blockIdx.x - NDST;
        cnt[t] = 0;
        __syncthreads();
        int len = cursor_s[b]; if (len > BCAPS) len = BCAPS;
        const unsigned short* p = bucket_s + (size_t)b * BCAPS;
        for (int i = t; i < len; i += 512)
            atomicAdd(&cnt[p[i]], 1);
        __syncthreads();
        int n0 = b << 9;
        if (n0 + t < NTOT) deg_out[n0 + t] = cnt[t];
    }
}

// 3) transpose inputs [SLI][FEAT][NODE] (f32) -> xs [NTOT][FEAT] (bf16), scaled by
//    rsqrt(deg_out). float4 global loads, packed 2xbf16 uint stores.
__global__ __launch_bounds__(256) void k_transpose(const float* __restrict__ in,
                                                   const int* __restrict__ deg_out,
                                                   unsigned short* __restrict__ xs) {
    __shared__ float tile[64][65];
    int sli = blockIdx.y;
    int n0  = blockIdx.x * 64;
    int t   = threadIdx.x;
    int fx  = t & 15;        // node quad
    int fr  = t >> 4;        // feat
    const float* ip = in + (size_t)sli * FEAT * NODE;
    int nq = n0 + fx * 4;
#pragma unroll
    for (int i = 0; i < 4; ++i) {
        int f = fr + i * 16;
        float4 v = {0.f, 0.f, 0.f, 0.f};
        if (nq < NODE) v = *(const float4*)(ip + (size_t)f * NODE + nq);  // coalesced 16B
        tile[f][fx * 4 + 0] = v.x;
        tile[f][fx * 4 + 1] = v.y;
        tile[f][fx * 4 + 2] = v.z;
        tile[f][fx * 4 + 3] = v.w;
    }
    __syncthreads();
    int h  = t & 31;         // feat pair: feats 2h, 2h+1
    int nr = t >> 5;
#pragma unroll
    for (int i = 0; i < 8; ++i) {
        int nl   = nr + i * 8;
        int node = n0 + nl;
        if (node < NODE) {
            int n = sli * NODE + node;
            int d = deg_out[n];
            float sc = rsqrtf(d > 0 ? (float)d : 1.f);
            unsigned lo = f2bf(tile[2 * h][nl] * sc);
            unsigned hi = f2bf(tile[2 * h + 1][nl] * sc);
            *(unsigned*)(xs + (size_t)n * 64 + 2 * h) = lo | (hi << 16);  // coalesced
        }
    }
}

// 4) fused ELL gather (8-lane x 16B, two rows in flight, zero-pad row -> no
//    divergence) + MFMA dense + bias + LeakyReLU + transposed store.
//    Verified 72-74us / VGPR 36 / Occ 55% (R0/R5/R6); FETCH 147MB is the
//    multi-XCD structural floor (~141MB computed) -> untouched.
__global__ __launch_bounds__(256) void k_agg_gemm(const int* __restrict__ deg_in,
                                                  const int* __restrict__ col_ell,
                                                  const unsigned short* __restrict__ xs,
                                                  const float* __restrict__ W,
                                                  const float* __restrict__ b,
                                                  float* __restrict__ out) {
    // LDS: av [64][72] bf16 @0 (9216) | wt [64][72] bf16 @9216 (9216) = 18432 B
    // otile [64][65] f32 (16640) aliases av+wt after the post-MFMA barrier.
    __shared__ char lds[18432];
    unsigned short* av = (unsigned short*)lds;
    unsigned short* wt = (unsigned short*)(lds + 9216);
    float (*otile)[65] = (float(*)[65])lds;

    int t    = threadIdx.x;
    int lane = t & 63;
    int w    = t >> 6;          // wave 0..3
    int g8   = lane >> 3;       // edge group 0..7
    int f8   = lane & 7;        // feat octet: feats 8*f8 .. 8*f8+7
    int sli  = blockIdx.y;
    int n0   = blockIdx.x * 64;

    // ---- stage Wt[out][feat] = bf16(W[feat][out]) ----
#pragma unroll
    for (int i = 0; i < 16; ++i) {
        int idx = i * 256 + t;          // idx = f*64 + o
        int f = idx >> 6, o = idx & 63;
        wt[o * 72 + f] = f2bf(W[idx]);
    }

    // ---- gather: wave w owns rows [m0, m0+16), two rows in flight ----
    int m0 = w * 16;
    for (int ii = 0; ii < 16; ii += 2) {
        int rowA = m0 + ii, rowB = rowA + 1;
        int nodeA = n0 + rowA, nodeB = n0 + rowB;
        int nA = sli * NODE + nodeA, nB = sli * NODE + nodeB;
        int dA = (nodeA < NODE) ? deg_in[nA] : 0;
        int dB = (nodeB < NODE) ? deg_in[nB] : 0;
        int degA = dA < CAP ? dA : CAP;
        int degB = dB < CAP ? dB : CAP;
        // pad lanes point at the zeroed xs row NTOT -> no guards in inner loop
        int cA = (lane < degA) ? col_ell[(size_t)nA * CAP + lane] : NTOT;  // coalesced
        int cB = (lane < degB) ? col_ell[(size_t)nB * CAP + lane] : NTOT;
        float accA[8] = {0,0,0,0,0,0,0,0};
        float accB[8] = {0,0,0,0,0,0,0,0};
        int gmax = degA > degB ? degA : degB;
        int groups = (gmax + 7) >> 3;
#pragma unroll 2
        for (int j = 0; j < groups; ++j) {
            int idx = 8 * j + g8;
            int sA = __shfl(cA, idx, 64);
            int sB = __shfl(cB, idx, 64);
            uint4 vA = *(const uint4*)(xs + (size_t)sA * 64 + f8 * 8);   // 16B, two rows
            uint4 vB = *(const uint4*)(xs + (size_t)sB * 64 + f8 * 8);   // in flight
            accA[0] += __uint_as_float(vA.x << 16);
            accA[1] += __uint_as_float(vA.x & 0xffff0000u);
            accA[2] += __uint_as_float(vA.y << 16);
            accA[3] += __uint_as_float(vA.y & 0xffff0000u);
            accA[4] += __uint_as_float(vA.z << 16);
            accA[5] += __uint_as_float(vA.z & 0xffff0000u);
            accA[6] += __uint_as_float(vA.w << 16);
            accA[7] += __uint_as_float(vA.w & 0xffff0000u);
            accB[0] += __uint_as_float(vB.x << 16);
            accB[1] += __uint_as_float(vB.x & 0xffff0000u);
            accB[2] += __uint_as_float(vB.y << 16);
            accB[3] += __uint_as_float(vB.y & 0xffff0000u);
            accB[4] += __uint_as_float(vB.z << 16);
            accB[5] += __uint_as_float(vB.z & 0xffff0000u);
            accB[6] += __uint_as_float(vB.w << 16);
            accB[7] += __uint_as_float(vB.w & 0xffff0000u);
        }
        // reduce over the 8 edge groups (lanes with same f8, stride 8)
#pragma unroll
        for (int k = 0; k < 8; ++k) {
            accA[k] += __shfl_xor(accA[k], 8, 64);
            accA[k] += __shfl_xor(accA[k], 16, 64);
            accA[k] += __shfl_xor(accA[k], 32, 64);
            accB[k] += __shfl_xor(accB[k], 8, 64);
            accB[k] += __shfl_xor(accB[k], 16, 64);
            accB[k] += __shfl_xor(accB[k], 32, 64);
        }
        if (g8 == 0) {    // lanes 0..7 hold feats 8*f8..8*f8+7
            float scA = rsqrtf(dA > 0 ? (float)dA : 1.f);
            float scB = rsqrtf(dB > 0 ? (float)dB : 1.f);
            uint4 hv;
            hv.x = (unsigned)f2bf(accA[0] * scA) | ((unsigned)f2bf(accA[1] * scA) << 16);
            hv.y = (unsigned)f2bf(accA[2] * scA) | ((unsigned)f2bf(accA[3] * scA) << 16);
            hv.z = (unsigned)f2bf(accA[4] * scA) | ((unsigned)f2bf(accA[5] * scA) << 16);
            hv.w = (unsigned)f2bf(accA[6] * scA) | ((unsigned)f2bf(accA[7] * scA) << 16);
            ((uint4*)(av + rowA * 72))[f8] = hv;
            hv.x = (unsigned)f2bf(accB[0] * scB) | ((unsigned)f2bf(accB[1] * scB) << 16);
            hv.y = (unsigned)f2bf(accB[2] * scB) | ((unsigned)f2bf(accB[3] * scB) << 16);
            hv.z = (unsigned)f2bf(accB[4] * scB) | ((unsigned)f2bf(accB[5] * scB) << 16);
            hv.w = (unsigned)f2bf(accB[6] * scB) | ((unsigned)f2bf(accB[7] * scB) << 16);
            ((uint4*)(av + rowB * 72))[f8] = hv;
        }
    }

    __syncthreads();   // wt + av complete

    // ---- MFMA: O[16 nodes][64 outs] per wave, K=64 ----
    int q = lane >> 4, r16 = lane & 15;
    bf16x8 afr[2], bfr[4][2];
#pragma unroll
    for (int ks = 0; ks < 2; ++ks)
        afr[ks] = *(const bf16x8*)(av + (m0 + r16) * 72 + ks * 32 + q * 8);
#pragma unroll
    for (int nt = 0; nt < 4; ++nt)
#pragma unroll
        for (int ks = 0; ks < 2; ++ks)
            bfr[nt][ks] = *(const bf16x8*)(wt + (nt * 16 + r16) * 72 + ks * 32 + q * 8);

    f32x4 acc4[4];
#pragma unroll
    for (int nt = 0; nt < 4; ++nt) acc4[nt] = (f32x4){0.f, 0.f, 0.f, 0.f};
#pragma unroll
    for (int nt = 0; nt < 4; ++nt)
#pragma unroll
        for (int ks = 0; ks < 2; ++ks)
            acc4[nt] = __builtin_amdgcn_mfma_f32_16x16x32_bf16(afr[ks], bfr[nt][ks], acc4[nt], 0, 0, 0);
    __syncthreads();   // av/wt reads done; safe to alias otile

    // ---- epilogue: bias + LeakyReLU -> otile[out][node_local] ----
#pragma unroll
    for (int nt = 0; nt < 4; ++nt) {
        int oc = nt * 16 + r16;
        float bias = b[oc];
#pragma unroll
        for (int r = 0; r < 4; ++r) {
            float v = acc4[nt][r] + bias;
            v = v > 0.f ? v : 0.01f * v;               // LeakyReLU
            otile[oc][m0 + q * 4 + r] = v;
        }
    }
    __syncthreads();

    const size_t obase = (size_t)sli * OUTF * NODE;
#pragma unroll
    for (int i = 0; i < 16; ++i) {
        int o    = w + i * 4;
        int node = n0 + lane;
        if (node < NODE)
            out[obase + (size_t)o * NODE + node] = otile[o][lane];   // coalesced
    }
}

// ---------------------------------------------------------------------------
extern "C" void kernel_launch(void* const* d_in, const int* in_sizes, int n_in,
                              void* d_out, int out_size, void* d_ws, size_t ws_size,
                              hipStream_t stream) {
    const float* inputs = (const float*)d_in[0];
    const float* W      = (const float*)d_in[1];
    const float* b      = (const float*)d_in[2];
    const int*   src    = (const int*)d_in[3];
    const int*   dst    = (const int*)d_in[4];
    float*       out    = (float*)d_out;
    const int E = in_sizes[3];

    // Workspace (~52.5 MB): deg_out | deg_in | col_ell | R
    // R holds bucket_d (12.16MB) + bucket_s (5.61MB) + cursors during build;
    // xs (+zero pad row NTOT) overlays R afterwards (20.48MB; build structs dead).
    char* ws = (char*)d_ws;
    int* deg_out = (int*)ws;
    int* deg_in  = (int*)(ws + (size_t)NTOT * 4);
    int* col_ell = (int*)(ws + (size_t)2 * NTOT * 4);
    char* R      = (char*)col_ell + (size_t)NTOT * CAP * 4;
    unsigned*       bucket_d = (unsigned*)R;                               // 12.16 MB
    unsigned short* bucket_s = (unsigned short*)(R + (size_t)NBD * BCAPD * 4); // 5.61 MB
    int*            cursors  = (int*)(R + (size_t)NBD * BCAPD * 4 + (size_t)NBS * BCAPS * 2);
    int* cursor_d = cursors;            // NBD ints
    int* cursor_s = cursors + NBD;      // NBS ints
    unsigned short* xs = (unsigned short*)R;   // (NTOT+1)*64 bf16 overlay (20.48 MB + pad)

    hipMemsetAsync(cursors, 0, (size_t)(NBD + NBS) * 4, stream);
    hipMemsetAsync(xs + (size_t)NTOT * 64, 0, 64 * sizeof(unsigned short), stream); // pad row

    int PB = (E + EPB - 1) / EPB;
    k_part<<<PB, 256, 0, stream>>>(src, dst, cursor_d, bucket_d, cursor_s, bucket_s, E);

    k_fin<<<NDST + NBS, 512, 0, stream>>>(cursor_d, bucket_d, cursor_s, bucket_s,
                                          col_ell, deg_in, deg_out);

    dim3 tgrid((NODE + 63) / 64, SLI);
    k_transpose<<<tgrid, 256, 0, stream>>>(inputs, deg_out, xs);

    k_agg_gemm<<<tgrid, 256, 0, stream>>>(deg_in, col_ell, xs, W, b, out);
}